// Round 2
// baseline (946.150 us; speedup 1.0000x reference)
//
#include <hip/hip_runtime.h>
#include <hip/hip_bf16.h>

#define NNODES 50000
#define NEDGES 800000
#define FIN 128
#define HID 32
#define HEADS 8
#define NG 64
#define NEG_SLOPE 0.2f

static __device__ __forceinline__ float leaky(float x) {
    return x > 0.f ? x : NEG_SLOPE * x;
}

// ---------------- zero init ----------------
__global__ void zero_kernel(int* deg, float* poolcnt) {
    int i = blockIdx.x * 256 + threadIdx.x;
    if (i < NNODES) deg[i] = 0;
    if (i < NG * HID + NG) poolcnt[i] = 0.f;
}

// ---------------- degree histogram ----------------
__global__ void deg_kernel(const int* __restrict__ ei, int* __restrict__ deg) {
    int e = blockIdx.x * 256 + threadIdx.x;
    if (e < NEDGES) {
        int d = ei[NEDGES + e];   // dst row
        atomicAdd(&deg[d], 1);
    }
}

// ---------------- block-wise exclusive scan ----------------
__global__ void scan_block(const int* __restrict__ in, int n, int* __restrict__ out_excl,
                           int* __restrict__ bsums) {
    __shared__ int s[256];
    int t = threadIdx.x;
    int i = blockIdx.x * 256 + t;
    int v = (i < n) ? in[i] : 0;
    s[t] = v;
    __syncthreads();
    for (int off = 1; off < 256; off <<= 1) {
        int x = (t >= off) ? s[t - off] : 0;
        __syncthreads();
        s[t] += x;
        __syncthreads();
    }
    if (i < n) out_excl[i] = s[t] - v;
    if (bsums && t == 255) bsums[blockIdx.x] = s[255];
}

__global__ void scan_add(int* __restrict__ row, const int* __restrict__ boffs,
                         int* __restrict__ cursor) {
    int i = blockIdx.x * 256 + threadIdx.x;
    if (i < NNODES) {
        int r = row[i] + boffs[blockIdx.x];
        row[i] = r;
        cursor[i] = r;
    }
}

// ---------------- scatter edges into CSR ----------------
__global__ void scatter_kernel(const int* __restrict__ ei, int* __restrict__ cursor,
                               int* __restrict__ csr_src) {
    int e = blockIdx.x * 256 + threadIdx.x;
    if (e < NEDGES) {
        int s = ei[e];
        int d = ei[NEDGES + e];
        int pos = atomicAdd(&cursor[d], 1);
        csr_src[pos] = s;
    }
}

// ---------------- GEMM1: h1[N,256] = x[N,128] @ W1[128,256] ----------------
__global__ __launch_bounds__(256) void gemm1_kernel(const float* __restrict__ x,
                                                    const float* __restrict__ W,
                                                    float* __restrict__ h1) {
    __shared__ float xs[64 * 132];   // 64 rows x 128 K, stride 132 (pad)
    __shared__ float wsh[128 * 64];  // 128 K x 64 cols
    int t = threadIdx.x;
    int rb = blockIdx.x * 64;
    int cb = blockIdx.y * 64;
#pragma unroll
    for (int i = 0; i < 8; ++i) {
        int f = t + i * 256;      // 0..2047
        int row = f >> 5;         // 32 float4 per row
        int c4 = f & 31;
        float4 v = make_float4(0.f, 0.f, 0.f, 0.f);
        int gr = rb + row;
        if (gr < NNODES) v = *(const float4*)(x + gr * FIN + c4 * 4);
        *(float4*)(xs + row * 132 + c4 * 4) = v;
    }
#pragma unroll
    for (int i = 0; i < 8; ++i) {
        int f = t + i * 256;      // 0..2047
        int k = f >> 4;           // 16 float4 per row
        int c4 = f & 15;
        float4 v = *(const float4*)(W + k * 256 + cb + c4 * 4);
        *(float4*)(wsh + k * 64 + c4 * 4) = v;
    }
    __syncthreads();
    int tx = t & 15, ty = t >> 4;
    float acc[4][4] = {};
#pragma unroll 8
    for (int k = 0; k < 128; ++k) {
        float a0 = xs[(ty * 4 + 0) * 132 + k];
        float a1 = xs[(ty * 4 + 1) * 132 + k];
        float a2 = xs[(ty * 4 + 2) * 132 + k];
        float a3 = xs[(ty * 4 + 3) * 132 + k];
        float4 b = *(float4*)(wsh + k * 64 + tx * 4);
        acc[0][0] += a0 * b.x; acc[0][1] += a0 * b.y; acc[0][2] += a0 * b.z; acc[0][3] += a0 * b.w;
        acc[1][0] += a1 * b.x; acc[1][1] += a1 * b.y; acc[1][2] += a1 * b.z; acc[1][3] += a1 * b.w;
        acc[2][0] += a2 * b.x; acc[2][1] += a2 * b.y; acc[2][2] += a2 * b.z; acc[2][3] += a2 * b.w;
        acc[3][0] += a3 * b.x; acc[3][1] += a3 * b.y; acc[3][2] += a3 * b.z; acc[3][3] += a3 * b.w;
    }
#pragma unroll
    for (int i = 0; i < 4; ++i) {
        int gr = rb + ty * 4 + i;
        if (gr < NNODES) {
            float4 v = make_float4(acc[i][0], acc[i][1], acc[i][2], acc[i][3]);
            *(float4*)(h1 + gr * 256 + cb + tx * 4) = v;
        }
    }
}

// ---------------- al1: per-node attention logits, layer 1 ----------------
// block = 256 threads = 4 nodes x 64 lanes; lane l covers cols l*4..l*4+3
__global__ __launch_bounds__(256) void al1_kernel(const float* __restrict__ h1,
                                                  const float* __restrict__ a_src,
                                                  const float* __restrict__ a_dst,
                                                  float* __restrict__ al_s,
                                                  float* __restrict__ al_d) {
    int t = threadIdx.x;
    int l = t & 63;
    int n = blockIdx.x * 4 + (t >> 6);
    if (n >= NNODES) return;
    float4 v = *(const float4*)(h1 + n * 256 + l * 4);
    float4 as = *(const float4*)(a_src + l * 4);
    float4 ad = *(const float4*)(a_dst + l * 4);
    float ps = v.x * as.x + v.y * as.y + v.z * as.z + v.w * as.w;
    float pd = v.x * ad.x + v.y * ad.y + v.z * ad.z + v.w * ad.w;
    // reduce over 8-lane groups (one head = 8 lanes x 4 cols)
    ps += __shfl_xor(ps, 1); pd += __shfl_xor(pd, 1);
    ps += __shfl_xor(ps, 2); pd += __shfl_xor(pd, 2);
    ps += __shfl_xor(ps, 4); pd += __shfl_xor(pd, 4);
    if ((l & 7) == 0) {
        int h = l >> 3;
        al_s[n * HEADS + h] = ps;
        al_d[n * HEADS + h] = pd;
    }
}

// ---------------- gather layer 1: softmax-attention aggregate + ReLU ----------------
// one block (256 thr) per dst node; thread t -> head t>>5, col t
__global__ __launch_bounds__(256) void gather1_kernel(const float* __restrict__ h1,
                                                      const float* __restrict__ al_s,
                                                      const float* __restrict__ al_d,
                                                      const int* __restrict__ row_start,
                                                      const int* __restrict__ csr_src,
                                                      const float* __restrict__ b1,
                                                      float* __restrict__ out1) {
    int n = blockIdx.x;
    int t = threadIdx.x;
    int h = t >> 5;
    float ad = al_d[n * HEADS + h];
    // self loop
    float p = __expf(leaky(al_s[n * HEADS + h] + ad));
    float z = p;
    float acc = p * h1[n * 256 + t];
    int beg = row_start[n];
    int end = (n + 1 < NNODES) ? row_start[n + 1] : NEDGES;
    for (int i = beg; i < end; ++i) {
        int s = csr_src[i];
        float pe = __expf(leaky(al_s[s * HEADS + h] + ad));
        z += pe;
        acc += pe * h1[s * 256 + t];
    }
    float o = acc / z + b1[t];
    out1[n * 256 + t] = o > 0.f ? o : 0.f;
}

// ---------------- GEMM2: h2[N,32] = out1[N,256] @ W2[256,32] ----------------
__global__ __launch_bounds__(256) void gemm2_kernel(const float* __restrict__ x,
                                                    const float* __restrict__ W,
                                                    float* __restrict__ h2) {
    __shared__ float xs[128 * 68];  // 128 rows x 64 K-chunk, stride 68
    __shared__ float wsh[64 * 32];  // 64 K x 32 cols
    int t = threadIdx.x;
    int rb = blockIdx.x * 128;
    int tx = t & 7, ty = t >> 3;    // tx: col group (4 cols), ty: row group (4 rows)
    float acc[4][4] = {};
    for (int kb = 0; kb < 256; kb += 64) {
        __syncthreads();
#pragma unroll
        for (int i = 0; i < 8; ++i) {
            int f = t + i * 256;     // 0..2047 float4 slots
            int row = f >> 4;        // 16 float4 per row
            int c4 = f & 15;
            float4 v = make_float4(0.f, 0.f, 0.f, 0.f);
            int gr = rb + row;
            if (gr < NNODES) v = *(const float4*)(x + gr * 256 + kb + c4 * 4);
            *(float4*)(xs + row * 68 + c4 * 4) = v;
        }
#pragma unroll
        for (int i = 0; i < 2; ++i) {
            int f = t + i * 256;     // 0..511 float4 slots
            int k = f >> 3;          // 8 float4 per row
            int c4 = f & 7;
            float4 v = *(const float4*)(W + (kb + k) * 32 + c4 * 4);
            *(float4*)(wsh + k * 32 + c4 * 4) = v;
        }
        __syncthreads();
#pragma unroll 8
        for (int kk = 0; kk < 64; ++kk) {
            float a0 = xs[(ty * 4 + 0) * 68 + kk];
            float a1 = xs[(ty * 4 + 1) * 68 + kk];
            float a2 = xs[(ty * 4 + 2) * 68 + kk];
            float a3 = xs[(ty * 4 + 3) * 68 + kk];
            float4 b = *(float4*)(wsh + kk * 32 + tx * 4);
            acc[0][0] += a0 * b.x; acc[0][1] += a0 * b.y; acc[0][2] += a0 * b.z; acc[0][3] += a0 * b.w;
            acc[1][0] += a1 * b.x; acc[1][1] += a1 * b.y; acc[1][2] += a1 * b.z; acc[1][3] += a1 * b.w;
            acc[2][0] += a2 * b.x; acc[2][1] += a2 * b.y; acc[2][2] += a2 * b.z; acc[2][3] += a2 * b.w;
            acc[3][0] += a3 * b.x; acc[3][1] += a3 * b.y; acc[3][2] += a3 * b.z; acc[3][3] += a3 * b.w;
        }
    }
#pragma unroll
    for (int i = 0; i < 4; ++i) {
        int gr = rb + ty * 4 + i;
        if (gr < NNODES) {
            float4 v = make_float4(acc[i][0], acc[i][1], acc[i][2], acc[i][3]);
            *(float4*)(h2 + gr * 32 + tx * 4) = v;
        }
    }
}

// ---------------- al2 ----------------
// block = 256 = 8 nodes x 32 lanes
__global__ __launch_bounds__(256) void al2_kernel(const float* __restrict__ h2,
                                                  const float* __restrict__ a_src,
                                                  const float* __restrict__ a_dst,
                                                  float* __restrict__ al_s,
                                                  float* __restrict__ al_d) {
    int t = threadIdx.x;
    int l = t & 31;
    int n = blockIdx.x * 8 + (t >> 5);
    if (n >= NNODES) return;
    float v = h2[n * HID + l];
    float ps = v * a_src[l];
    float pd = v * a_dst[l];
    ps += __shfl_xor(ps, 1);  pd += __shfl_xor(pd, 1);
    ps += __shfl_xor(ps, 2);  pd += __shfl_xor(pd, 2);
    ps += __shfl_xor(ps, 4);  pd += __shfl_xor(pd, 4);
    ps += __shfl_xor(ps, 8);  pd += __shfl_xor(pd, 8);
    ps += __shfl_xor(ps, 16); pd += __shfl_xor(pd, 16);
    if (l == 0) {
        al_s[n] = ps;
        al_d[n] = pd;
    }
}

// ---------------- gather layer 2 + mean-pool accumulate ----------------
// block 256 = 8 nodes x 32 lanes
__global__ __launch_bounds__(256) void gather2_kernel(const float* __restrict__ h2,
                                                      const float* __restrict__ al_s,
                                                      const float* __restrict__ al_d,
                                                      const int* __restrict__ row_start,
                                                      const int* __restrict__ csr_src,
                                                      const float* __restrict__ b2,
                                                      const int* __restrict__ batch,
                                                      float* __restrict__ pool,
                                                      float* __restrict__ cnt) {
    int t = threadIdx.x;
    int c = t & 31;
    int n = blockIdx.x * 8 + (t >> 5);
    if (n >= NNODES) return;
    float ad = al_d[n];
    float p = __expf(leaky(al_s[n] + ad));
    float z = p;
    float acc = p * h2[n * HID + c];
    int beg = row_start[n];
    int end = (n + 1 < NNODES) ? row_start[n + 1] : NEDGES;
    for (int i = beg; i < end; ++i) {
        int s = csr_src[i];
        float pe = __expf(leaky(al_s[s] + ad));
        z += pe;
        acc += pe * h2[s * HID + c];
    }
    float o = acc / z + b2[c];
    int g = batch[n];
    atomicAdd(&pool[g * HID + c], o);
    if (c == 0) atomicAdd(&cnt[g], 1.0f);
}

// ---------------- finalize ----------------
__global__ void finalize_kernel(const float* __restrict__ pool, const float* __restrict__ cnt,
                                float* __restrict__ out) {
    int i = blockIdx.x * 256 + threadIdx.x;
    if (i < NG * HID) {
        int g = i >> 5;
        float c = cnt[g];
        out[i] = pool[i] / (c > 1.f ? c : 1.f);
    }
}

extern "C" void kernel_launch(void* const* d_in, const int* in_sizes, int n_in,
                              void* d_out, int out_size, void* d_ws, size_t ws_size,
                              hipStream_t stream) {
    const float* x      = (const float*)d_in[0];
    const int*   ei     = (const int*)d_in[1];
    // d_in[2] = edge_attr (unused)
    const int*   batch  = (const int*)d_in[3];
    const float* W1     = (const float*)d_in[4];
    const float* a_src1 = (const float*)d_in[5];
    const float* a_dst1 = (const float*)d_in[6];
    const float* b1     = (const float*)d_in[7];
    const float* W2     = (const float*)d_in[8];
    const float* a_src2 = (const float*)d_in[9];
    const float* a_dst2 = (const float*)d_in[10];
    const float* b2     = (const float*)d_in[11];
    float* out = (float*)d_out;

    char* ws = (char*)d_ws;
    size_t off = 0;
    auto alloc = [&](size_t bytes) {
        size_t o = off;
        off = (off + bytes + 255) & ~(size_t)255;
        return o;
    };
    float* h1     = (float*)(ws + alloc((size_t)NNODES * 256 * 4));
    float* out1   = (float*)(ws + alloc((size_t)NNODES * 256 * 4));
    float* h2     = (float*)(ws + alloc((size_t)NNODES * HID * 4));
    float* al_s1  = (float*)(ws + alloc((size_t)NNODES * HEADS * 4));
    float* al_d1  = (float*)(ws + alloc((size_t)NNODES * HEADS * 4));
    float* al_s2  = (float*)(ws + alloc((size_t)NNODES * 4));
    float* al_d2  = (float*)(ws + alloc((size_t)NNODES * 4));
    float* pool   = (float*)(ws + alloc((size_t)NG * HID * 4 + NG * 4)); // pool + cnt contiguous
    float* cnt    = pool + NG * HID;
    int*   deg    = (int*)(ws + alloc((size_t)NNODES * 4));
    int*   rowst  = (int*)(ws + alloc((size_t)NNODES * 4));
    int*   cursor = (int*)(ws + alloc((size_t)NNODES * 4));
    int*   bsums  = (int*)(ws + alloc(256 * 4));
    int*   boffs  = (int*)(ws + alloc(256 * 4));
    int*   csr    = (int*)(ws + alloc((size_t)NEDGES * 4));
    (void)ws_size;

    int nb_nodes = (NNODES + 255) / 256;      // 196
    int nb_edges = (NEDGES + 255) / 256;      // 3125

    zero_kernel<<<nb_nodes, 256, 0, stream>>>(deg, pool);
    deg_kernel<<<nb_edges, 256, 0, stream>>>(ei, deg);
    scan_block<<<nb_nodes, 256, 0, stream>>>(deg, NNODES, rowst, bsums);
    scan_block<<<1, 256, 0, stream>>>(bsums, nb_nodes, boffs, (int*)nullptr);
    scan_add<<<nb_nodes, 256, 0, stream>>>(rowst, boffs, cursor);
    scatter_kernel<<<nb_edges, 256, 0, stream>>>(ei, cursor, csr);

    dim3 g1((NNODES + 63) / 64, 4);
    gemm1_kernel<<<g1, 256, 0, stream>>>(x, W1, h1);
    al1_kernel<<<(NNODES + 3) / 4, 256, 0, stream>>>(h1, a_src1, a_dst1, al_s1, al_d1);
    gather1_kernel<<<NNODES, 256, 0, stream>>>(h1, al_s1, al_d1, rowst, csr, b1, out1);

    gemm2_kernel<<<(NNODES + 127) / 128, 256, 0, stream>>>(out1, W2, h2);
    al2_kernel<<<(NNODES + 7) / 8, 256, 0, stream>>>(h2, a_src2, a_dst2, al_s2, al_d2);
    gather2_kernel<<<(NNODES + 7) / 8, 256, 0, stream>>>(h2, al_s2, al_d2, rowst, csr, b2,
                                                         batch, pool, cnt);
    finalize_kernel<<<(NG * HID + 255) / 256, 256, 0, stream>>>(pool, cnt, out);
}

// Round 3
// 556.304 us; speedup vs baseline: 1.7008x; 1.7008x over previous
//
#include <hip/hip_runtime.h>
#include <hip/hip_bf16.h>

#define NNODES 50000
#define NEDGES 800000
#define FIN 128
#define HID 32
#define HEADS 8
#define NG 64
#define NEG_SLOPE 0.2f

static __device__ __forceinline__ float leaky(float x) {
    return x > 0.f ? x : NEG_SLOPE * x;
}

// ---------------- zero init ----------------
__global__ void zero_kernel(int* deg) {
    int i = blockIdx.x * 256 + threadIdx.x;
    if (i < NNODES) deg[i] = 0;
}

// ---------------- degree histogram ----------------
__global__ void deg_kernel(const int* __restrict__ ei, int* __restrict__ deg) {
    int e = blockIdx.x * 256 + threadIdx.x;
    if (e < NEDGES) {
        int d = ei[NEDGES + e];   // dst row
        atomicAdd(&deg[d], 1);
    }
}

// ---------------- block-wise exclusive scan ----------------
__global__ void scan_block(const int* __restrict__ in, int n, int* __restrict__ out_excl,
                           int* __restrict__ bsums) {
    __shared__ int s[256];
    int t = threadIdx.x;
    int i = blockIdx.x * 256 + t;
    int v = (i < n) ? in[i] : 0;
    s[t] = v;
    __syncthreads();
    for (int off = 1; off < 256; off <<= 1) {
        int x = (t >= off) ? s[t - off] : 0;
        __syncthreads();
        s[t] += x;
        __syncthreads();
    }
    if (i < n) out_excl[i] = s[t] - v;
    if (bsums && t == 255) bsums[blockIdx.x] = s[255];
}

__global__ void scan_add(int* __restrict__ row, const int* __restrict__ boffs,
                         int* __restrict__ cursor) {
    int i = blockIdx.x * 256 + threadIdx.x;
    if (i < NNODES) {
        int r = row[i] + boffs[blockIdx.x];
        row[i] = r;
        cursor[i] = r;
    }
}

// ---------------- scatter edges into CSR ----------------
__global__ void scatter_kernel(const int* __restrict__ ei, int* __restrict__ cursor,
                               int* __restrict__ csr_src) {
    int e = blockIdx.x * 256 + threadIdx.x;
    if (e < NEDGES) {
        int s = ei[e];
        int d = ei[NEDGES + e];
        int pos = atomicAdd(&cursor[d], 1);
        csr_src[pos] = s;
    }
}

// ---------------- GEMM1: h1[N,256] = x[N,128] @ W1[128,256] ----------------
__global__ __launch_bounds__(256) void gemm1_kernel(const float* __restrict__ x,
                                                    const float* __restrict__ W,
                                                    float* __restrict__ h1) {
    __shared__ float xs[64 * 132];   // 64 rows x 128 K, stride 132 (pad)
    __shared__ float wsh[128 * 64];  // 128 K x 64 cols
    int t = threadIdx.x;
    int rb = blockIdx.x * 64;
    int cb = blockIdx.y * 64;
#pragma unroll
    for (int i = 0; i < 8; ++i) {
        int f = t + i * 256;      // 0..2047
        int row = f >> 5;         // 32 float4 per row
        int c4 = f & 31;
        float4 v = make_float4(0.f, 0.f, 0.f, 0.f);
        int gr = rb + row;
        if (gr < NNODES) v = *(const float4*)(x + gr * FIN + c4 * 4);
        *(float4*)(xs + row * 132 + c4 * 4) = v;
    }
#pragma unroll
    for (int i = 0; i < 8; ++i) {
        int f = t + i * 256;      // 0..2047
        int k = f >> 4;           // 16 float4 per row
        int c4 = f & 15;
        float4 v = *(const float4*)(W + k * 256 + cb + c4 * 4);
        *(float4*)(wsh + k * 64 + c4 * 4) = v;
    }
    __syncthreads();
    int tx = t & 15, ty = t >> 4;
    float acc[4][4] = {};
#pragma unroll 8
    for (int k = 0; k < 128; ++k) {
        float a0 = xs[(ty * 4 + 0) * 132 + k];
        float a1 = xs[(ty * 4 + 1) * 132 + k];
        float a2 = xs[(ty * 4 + 2) * 132 + k];
        float a3 = xs[(ty * 4 + 3) * 132 + k];
        float4 b = *(float4*)(wsh + k * 64 + tx * 4);
        acc[0][0] += a0 * b.x; acc[0][1] += a0 * b.y; acc[0][2] += a0 * b.z; acc[0][3] += a0 * b.w;
        acc[1][0] += a1 * b.x; acc[1][1] += a1 * b.y; acc[1][2] += a1 * b.z; acc[1][3] += a1 * b.w;
        acc[2][0] += a2 * b.x; acc[2][1] += a2 * b.y; acc[2][2] += a2 * b.z; acc[2][3] += a2 * b.w;
        acc[3][0] += a3 * b.x; acc[3][1] += a3 * b.y; acc[3][2] += a3 * b.z; acc[3][3] += a3 * b.w;
    }
#pragma unroll
    for (int i = 0; i < 4; ++i) {
        int gr = rb + ty * 4 + i;
        if (gr < NNODES) {
            float4 v = make_float4(acc[i][0], acc[i][1], acc[i][2], acc[i][3]);
            *(float4*)(h1 + gr * 256 + cb + tx * 4) = v;
        }
    }
}

// ---------------- al1: per-node attention logits, layer 1 ----------------
__global__ __launch_bounds__(256) void al1_kernel(const float* __restrict__ h1,
                                                  const float* __restrict__ a_src,
                                                  const float* __restrict__ a_dst,
                                                  float* __restrict__ al_s,
                                                  float* __restrict__ al_d) {
    int t = threadIdx.x;
    int l = t & 63;
    int n = blockIdx.x * 4 + (t >> 6);
    if (n >= NNODES) return;
    float4 v = *(const float4*)(h1 + n * 256 + l * 4);
    float4 as = *(const float4*)(a_src + l * 4);
    float4 ad = *(const float4*)(a_dst + l * 4);
    float ps = v.x * as.x + v.y * as.y + v.z * as.z + v.w * as.w;
    float pd = v.x * ad.x + v.y * ad.y + v.z * ad.z + v.w * ad.w;
    ps += __shfl_xor(ps, 1); pd += __shfl_xor(pd, 1);
    ps += __shfl_xor(ps, 2); pd += __shfl_xor(pd, 2);
    ps += __shfl_xor(ps, 4); pd += __shfl_xor(pd, 4);
    if ((l & 7) == 0) {
        int h = l >> 3;
        al_s[n * HEADS + h] = ps;
        al_d[n * HEADS + h] = pd;
    }
}

// ---------------- gather layer 1: softmax-attention aggregate + ReLU ----------------
__global__ __launch_bounds__(256) void gather1_kernel(const float* __restrict__ h1,
                                                      const float* __restrict__ al_s,
                                                      const float* __restrict__ al_d,
                                                      const int* __restrict__ row_start,
                                                      const int* __restrict__ csr_src,
                                                      const float* __restrict__ b1,
                                                      float* __restrict__ out1) {
    int n = blockIdx.x;
    int t = threadIdx.x;
    int h = t >> 5;
    float ad = al_d[n * HEADS + h];
    float p = __expf(leaky(al_s[n * HEADS + h] + ad));
    float z = p;
    float acc = p * h1[n * 256 + t];
    int beg = row_start[n];
    int end = (n + 1 < NNODES) ? row_start[n + 1] : NEDGES;
    for (int i = beg; i < end; ++i) {
        int s = csr_src[i];
        float pe = __expf(leaky(al_s[s * HEADS + h] + ad));
        z += pe;
        acc += pe * h1[s * 256 + t];
    }
    float o = acc / z + b1[t];
    out1[n * 256 + t] = o > 0.f ? o : 0.f;
}

// ---------------- GEMM2: h2[N,32] = out1[N,256] @ W2[256,32] ----------------
__global__ __launch_bounds__(256) void gemm2_kernel(const float* __restrict__ x,
                                                    const float* __restrict__ W,
                                                    float* __restrict__ h2) {
    __shared__ float xs[128 * 68];  // 128 rows x 64 K-chunk, stride 68
    __shared__ float wsh[64 * 32];  // 64 K x 32 cols
    int t = threadIdx.x;
    int rb = blockIdx.x * 128;
    int tx = t & 7, ty = t >> 3;
    float acc[4][4] = {};
    for (int kb = 0; kb < 256; kb += 64) {
        __syncthreads();
#pragma unroll
        for (int i = 0; i < 8; ++i) {
            int f = t + i * 256;     // 0..2047 float4 slots
            int row = f >> 4;        // 16 float4 per row
            int c4 = f & 15;
            float4 v = make_float4(0.f, 0.f, 0.f, 0.f);
            int gr = rb + row;
            if (gr < NNODES) v = *(const float4*)(x + gr * 256 + kb + c4 * 4);
            *(float4*)(xs + row * 68 + c4 * 4) = v;
        }
#pragma unroll
        for (int i = 0; i < 2; ++i) {
            int f = t + i * 256;     // 0..511 float4 slots
            int k = f >> 3;          // 8 float4 per row
            int c4 = f & 7;
            float4 v = *(const float4*)(W + (kb + k) * 32 + c4 * 4);
            *(float4*)(wsh + k * 32 + c4 * 4) = v;
        }
        __syncthreads();
#pragma unroll 8
        for (int kk = 0; kk < 64; ++kk) {
            float a0 = xs[(ty * 4 + 0) * 68 + kk];
            float a1 = xs[(ty * 4 + 1) * 68 + kk];
            float a2 = xs[(ty * 4 + 2) * 68 + kk];
            float a3 = xs[(ty * 4 + 3) * 68 + kk];
            float4 b = *(float4*)(wsh + kk * 32 + tx * 4);
            acc[0][0] += a0 * b.x; acc[0][1] += a0 * b.y; acc[0][2] += a0 * b.z; acc[0][3] += a0 * b.w;
            acc[1][0] += a1 * b.x; acc[1][1] += a1 * b.y; acc[1][2] += a1 * b.z; acc[1][3] += a1 * b.w;
            acc[2][0] += a2 * b.x; acc[2][1] += a2 * b.y; acc[2][2] += a2 * b.z; acc[2][3] += a2 * b.w;
            acc[3][0] += a3 * b.x; acc[3][1] += a3 * b.y; acc[3][2] += a3 * b.z; acc[3][3] += a3 * b.w;
        }
    }
#pragma unroll
    for (int i = 0; i < 4; ++i) {
        int gr = rb + ty * 4 + i;
        if (gr < NNODES) {
            float4 v = make_float4(acc[i][0], acc[i][1], acc[i][2], acc[i][3]);
            *(float4*)(h2 + gr * 32 + tx * 4) = v;
        }
    }
}

// ---------------- al2 ----------------
__global__ __launch_bounds__(256) void al2_kernel(const float* __restrict__ h2,
                                                  const float* __restrict__ a_src,
                                                  const float* __restrict__ a_dst,
                                                  float* __restrict__ al_s,
                                                  float* __restrict__ al_d) {
    int t = threadIdx.x;
    int l = t & 31;
    int n = blockIdx.x * 8 + (t >> 5);
    if (n >= NNODES) return;
    float v = h2[n * HID + l];
    float ps = v * a_src[l];
    float pd = v * a_dst[l];
    ps += __shfl_xor(ps, 1);  pd += __shfl_xor(pd, 1);
    ps += __shfl_xor(ps, 2);  pd += __shfl_xor(pd, 2);
    ps += __shfl_xor(ps, 4);  pd += __shfl_xor(pd, 4);
    ps += __shfl_xor(ps, 8);  pd += __shfl_xor(pd, 8);
    ps += __shfl_xor(ps, 16); pd += __shfl_xor(pd, 16);
    if (l == 0) {
        al_s[n] = ps;
        al_d[n] = pd;
    }
}

// ---------------- gather layer 2: per-node output, NO atomics ----------------
// block 256 = 8 nodes x 32 lanes; writes out2[N,32]
__global__ __launch_bounds__(256) void gather2_kernel(const float* __restrict__ h2,
                                                      const float* __restrict__ al_s,
                                                      const float* __restrict__ al_d,
                                                      const int* __restrict__ row_start,
                                                      const int* __restrict__ csr_src,
                                                      const float* __restrict__ b2,
                                                      float* __restrict__ out2) {
    int t = threadIdx.x;
    int c = t & 31;
    int n = blockIdx.x * 8 + (t >> 5);
    if (n >= NNODES) return;
    float ad = al_d[n];
    float p = __expf(leaky(al_s[n] + ad));
    float z = p;
    float acc = p * h2[n * HID + c];
    int beg = row_start[n];
    int end = (n + 1 < NNODES) ? row_start[n + 1] : NEDGES;
    for (int i = beg; i < end; ++i) {
        int s = csr_src[i];
        float pe = __expf(leaky(al_s[s] + ad));
        z += pe;
        acc += pe * h2[s * HID + c];
    }
    out2[n * HID + c] = acc / z + b2[c];
}

// ---------------- mean-pool: one block per graph, batch is sorted ----------------
__global__ __launch_bounds__(256) void pool_kernel(const float* __restrict__ out2,
                                                   const int* __restrict__ batch,
                                                   float* __restrict__ out) {
    __shared__ float red[256];
    int g = blockIdx.x;          // 0..63
    int t = threadIdx.x;
    int c = t & 31;
    int sub = t >> 5;            // 8 node-strided subgroups
    // lower_bound(batch, key): first idx with batch[idx] >= key (wave-uniform)
    int beg, end;
    {
        int lo = 0, hi = NNODES;
        while (lo < hi) { int mid = (lo + hi) >> 1; if (batch[mid] < g) lo = mid + 1; else hi = mid; }
        beg = lo;
        lo = beg; hi = NNODES;
        while (lo < hi) { int mid = (lo + hi) >> 1; if (batch[mid] < g + 1) lo = mid + 1; else hi = mid; }
        end = lo;
    }
    float s = 0.f;
    for (int n = beg + sub; n < end; n += 8) s += out2[n * HID + c];
    red[t] = s;
    __syncthreads();
    if (t < 32) {
        float tot = 0.f;
#pragma unroll
        for (int k = 0; k < 8; ++k) tot += red[c + 32 * k];
        int cnt = end - beg;
        out[g * HID + c] = tot / (float)(cnt > 0 ? cnt : 1);
    }
}

extern "C" void kernel_launch(void* const* d_in, const int* in_sizes, int n_in,
                              void* d_out, int out_size, void* d_ws, size_t ws_size,
                              hipStream_t stream) {
    const float* x      = (const float*)d_in[0];
    const int*   ei     = (const int*)d_in[1];
    // d_in[2] = edge_attr (unused)
    const int*   batch  = (const int*)d_in[3];
    const float* W1     = (const float*)d_in[4];
    const float* a_src1 = (const float*)d_in[5];
    const float* a_dst1 = (const float*)d_in[6];
    const float* b1     = (const float*)d_in[7];
    const float* W2     = (const float*)d_in[8];
    const float* a_src2 = (const float*)d_in[9];
    const float* a_dst2 = (const float*)d_in[10];
    const float* b2     = (const float*)d_in[11];
    float* out = (float*)d_out;

    char* ws = (char*)d_ws;
    size_t off = 0;
    auto alloc = [&](size_t bytes) {
        size_t o = off;
        off = (off + bytes + 255) & ~(size_t)255;
        return o;
    };
    float* h1     = (float*)(ws + alloc((size_t)NNODES * 256 * 4));
    float* out1   = (float*)(ws + alloc((size_t)NNODES * 256 * 4));
    float* h2     = (float*)(ws + alloc((size_t)NNODES * HID * 4));
    float* out2   = (float*)(ws + alloc((size_t)NNODES * HID * 4));
    float* al_s1  = (float*)(ws + alloc((size_t)NNODES * HEADS * 4));
    float* al_d1  = (float*)(ws + alloc((size_t)NNODES * HEADS * 4));
    float* al_s2  = (float*)(ws + alloc((size_t)NNODES * 4));
    float* al_d2  = (float*)(ws + alloc((size_t)NNODES * 4));
    int*   deg    = (int*)(ws + alloc((size_t)NNODES * 4));
    int*   rowst  = (int*)(ws + alloc((size_t)NNODES * 4));
    int*   cursor = (int*)(ws + alloc((size_t)NNODES * 4));
    int*   bsums  = (int*)(ws + alloc(256 * 4));
    int*   boffs  = (int*)(ws + alloc(256 * 4));
    int*   csr    = (int*)(ws + alloc((size_t)NEDGES * 4));
    (void)ws_size;

    int nb_nodes = (NNODES + 255) / 256;      // 196
    int nb_edges = (NEDGES + 255) / 256;      // 3125

    zero_kernel<<<nb_nodes, 256, 0, stream>>>(deg);
    deg_kernel<<<nb_edges, 256, 0, stream>>>(ei, deg);
    scan_block<<<nb_nodes, 256, 0, stream>>>(deg, NNODES, rowst, bsums);
    scan_block<<<1, 256, 0, stream>>>(bsums, nb_nodes, boffs, (int*)nullptr);
    scan_add<<<nb_nodes, 256, 0, stream>>>(rowst, boffs, cursor);
    scatter_kernel<<<nb_edges, 256, 0, stream>>>(ei, cursor, csr);

    dim3 g1((NNODES + 63) / 64, 4);
    gemm1_kernel<<<g1, 256, 0, stream>>>(x, W1, h1);
    al1_kernel<<<(NNODES + 3) / 4, 256, 0, stream>>>(h1, a_src1, a_dst1, al_s1, al_d1);
    gather1_kernel<<<NNODES, 256, 0, stream>>>(h1, al_s1, al_d1, rowst, csr, b1, out1);

    gemm2_kernel<<<(NNODES + 127) / 128, 256, 0, stream>>>(out1, W2, h2);
    al2_kernel<<<(NNODES + 7) / 8, 256, 0, stream>>>(h2, a_src2, a_dst2, al_s2, al_d2);
    gather2_kernel<<<(NNODES + 7) / 8, 256, 0, stream>>>(h2, al_s2, al_d2, rowst, csr, b2, out2);
    pool_kernel<<<NG, 256, 0, stream>>>(out2, batch, out);
}

// Round 4
// 501.197 us; speedup vs baseline: 1.8878x; 1.1100x over previous
//
#include <hip/hip_runtime.h>
#include <hip/hip_bf16.h>

#define NNODES 50000
#define NEDGES 800000
#define FIN 128
#define HID 32
#define HEADS 8
#define NG 64
#define NEG_SLOPE 0.2f

static __device__ __forceinline__ float leaky(float x) {
    return x > 0.f ? x : NEG_SLOPE * x;
}

// ---------------- zero init ----------------
__global__ void zero_kernel(int* deg) {
    int i = blockIdx.x * 256 + threadIdx.x;
    if (i < NNODES) deg[i] = 0;
}

// ---------------- degree histogram ----------------
__global__ void deg_kernel(const int* __restrict__ ei, int* __restrict__ deg) {
    int e = blockIdx.x * 256 + threadIdx.x;
    if (e < NEDGES) {
        int d = ei[NEDGES + e];   // dst row
        atomicAdd(&deg[d], 1);
    }
}

// ---------------- block-wise exclusive scan ----------------
__global__ void scan_block(const int* __restrict__ in, int n, int* __restrict__ out_excl,
                           int* __restrict__ bsums) {
    __shared__ int s[256];
    int t = threadIdx.x;
    int i = blockIdx.x * 256 + t;
    int v = (i < n) ? in[i] : 0;
    s[t] = v;
    __syncthreads();
    for (int off = 1; off < 256; off <<= 1) {
        int x = (t >= off) ? s[t - off] : 0;
        __syncthreads();
        s[t] += x;
        __syncthreads();
    }
    if (i < n) out_excl[i] = s[t] - v;
    if (bsums && t == 255) bsums[blockIdx.x] = s[255];
}

__global__ void scan_add(int* __restrict__ row, const int* __restrict__ boffs,
                         int* __restrict__ cursor) {
    int i = blockIdx.x * 256 + threadIdx.x;
    if (i < NNODES) {
        int r = row[i] + boffs[blockIdx.x];
        row[i] = r;
        cursor[i] = r;
    }
}

// ---------------- scatter edges into CSR ----------------
__global__ void scatter_kernel(const int* __restrict__ ei, int* __restrict__ cursor,
                               int* __restrict__ csr_src) {
    int e = blockIdx.x * 256 + threadIdx.x;
    if (e < NEDGES) {
        int s = ei[e];
        int d = ei[NEDGES + e];
        int pos = atomicAdd(&cursor[d], 1);
        csr_src[pos] = s;
    }
}

// ---------------- GEMM1: h1[N,256] = x[N,128] @ W1[128,256] ----------------
__global__ __launch_bounds__(256) void gemm1_kernel(const float* __restrict__ x,
                                                    const float* __restrict__ W,
                                                    float* __restrict__ h1) {
    __shared__ float xs[64 * 132];   // 64 rows x 128 K, stride 132 (pad)
    __shared__ float wsh[128 * 64];  // 128 K x 64 cols
    int t = threadIdx.x;
    int rb = blockIdx.x * 64;
    int cb = blockIdx.y * 64;
#pragma unroll
    for (int i = 0; i < 8; ++i) {
        int f = t + i * 256;      // 0..2047
        int row = f >> 5;         // 32 float4 per row
        int c4 = f & 31;
        float4 v = make_float4(0.f, 0.f, 0.f, 0.f);
        int gr = rb + row;
        if (gr < NNODES) v = *(const float4*)(x + gr * FIN + c4 * 4);
        *(float4*)(xs + row * 132 + c4 * 4) = v;
    }
#pragma unroll
    for (int i = 0; i < 8; ++i) {
        int f = t + i * 256;      // 0..2047
        int k = f >> 4;           // 16 float4 per row
        int c4 = f & 15;
        float4 v = *(const float4*)(W + k * 256 + cb + c4 * 4);
        *(float4*)(wsh + k * 64 + c4 * 4) = v;
    }
    __syncthreads();
    int tx = t & 15, ty = t >> 4;
    float acc[4][4] = {};
#pragma unroll 8
    for (int k = 0; k < 128; ++k) {
        float a0 = xs[(ty * 4 + 0) * 132 + k];
        float a1 = xs[(ty * 4 + 1) * 132 + k];
        float a2 = xs[(ty * 4 + 2) * 132 + k];
        float a3 = xs[(ty * 4 + 3) * 132 + k];
        float4 b = *(float4*)(wsh + k * 64 + tx * 4);
        acc[0][0] += a0 * b.x; acc[0][1] += a0 * b.y; acc[0][2] += a0 * b.z; acc[0][3] += a0 * b.w;
        acc[1][0] += a1 * b.x; acc[1][1] += a1 * b.y; acc[1][2] += a1 * b.z; acc[1][3] += a1 * b.w;
        acc[2][0] += a2 * b.x; acc[2][1] += a2 * b.y; acc[2][2] += a2 * b.z; acc[2][3] += a2 * b.w;
        acc[3][0] += a3 * b.x; acc[3][1] += a3 * b.y; acc[3][2] += a3 * b.z; acc[3][3] += a3 * b.w;
    }
#pragma unroll
    for (int i = 0; i < 4; ++i) {
        int gr = rb + ty * 4 + i;
        if (gr < NNODES) {
            float4 v = make_float4(acc[i][0], acc[i][1], acc[i][2], acc[i][3]);
            *(float4*)(h1 + gr * 256 + cb + tx * 4) = v;
        }
    }
}

// ---------------- al1: per-node attention logits, layer 1 ----------------
__global__ __launch_bounds__(256) void al1_kernel(const float* __restrict__ h1,
                                                  const float* __restrict__ a_src,
                                                  const float* __restrict__ a_dst,
                                                  float* __restrict__ al_s,
                                                  float* __restrict__ al_d) {
    int t = threadIdx.x;
    int l = t & 63;
    int n = blockIdx.x * 4 + (t >> 6);
    if (n >= NNODES) return;
    float4 v = *(const float4*)(h1 + n * 256 + l * 4);
    float4 as = *(const float4*)(a_src + l * 4);
    float4 ad = *(const float4*)(a_dst + l * 4);
    float ps = v.x * as.x + v.y * as.y + v.z * as.z + v.w * as.w;
    float pd = v.x * ad.x + v.y * ad.y + v.z * ad.z + v.w * ad.w;
    ps += __shfl_xor(ps, 1); pd += __shfl_xor(pd, 1);
    ps += __shfl_xor(ps, 2); pd += __shfl_xor(pd, 2);
    ps += __shfl_xor(ps, 4); pd += __shfl_xor(pd, 4);
    if ((l & 7) == 0) {
        int h = l >> 3;
        al_s[n * HEADS + h] = ps;
        al_d[n * HEADS + h] = pd;
    }
}

// ---------------- gather layer 1: 1 wave per node, float4 per lane ----------------
// lane l: head = l>>3, cols 4l..4l+3 (row is head-major so col = 4l).
// Edges in chunks of 8: staged lane l holds edge (l>>3), head (l&7);
// fma loop broadcasts src/pe via __shfl (no LDS, wave-synchronous).
__global__ __launch_bounds__(256) void gather1_kernel(const float* __restrict__ h1,
                                                      const float* __restrict__ al_s,
                                                      const float* __restrict__ al_d,
                                                      const int* __restrict__ row_start,
                                                      const int* __restrict__ csr_src,
                                                      const float* __restrict__ b1,
                                                      float* __restrict__ out1) {
    int t = threadIdx.x;
    int l = t & 63;
    int n = blockIdx.x * 4 + (t >> 6);
    if (n >= NNODES) return;
    int hs = l >> 3;           // fma-phase head AND staged-edge slot
    int h_st = l & 7;          // staging-phase head
    float ad_st = al_d[n * HEADS + h_st];

    // self loop
    float p = __expf(leaky(al_s[n * HEADS + hs] + al_d[n * HEADS + hs]));
    float z = p;
    float4 hrow = *(const float4*)(h1 + (size_t)n * 256 + l * 4);
    float4 acc = make_float4(p * hrow.x, p * hrow.y, p * hrow.z, p * hrow.w);

    int beg = row_start[n];
    int end = (n + 1 < NNODES) ? row_start[n + 1] : NEDGES;
    for (int i = beg; i < end; i += 8) {
        int rem = end - i;
        int src8 = n;          // padded slots read the (hot) self row with pe=0
        float pe8 = 0.f;
        if (hs < rem) {        // hs doubles as staged-edge slot
            src8 = csr_src[i + hs];
            pe8 = __expf(leaky(al_s[src8 * HEADS + h_st] + ad_st));
        }
#pragma unroll
        for (int j = 0; j < 8; ++j) {
            int   sj  = __shfl(src8, j * 8);
            float pej = __shfl(pe8, j * 8 + hs);
            float4 v = *(const float4*)(h1 + (size_t)sj * 256 + l * 4);
            z += pej;
            acc.x += pej * v.x; acc.y += pej * v.y;
            acc.z += pej * v.z; acc.w += pej * v.w;
        }
    }
    float4 bb = *(const float4*)(b1 + l * 4);
    float inv = 1.0f / z;
    float4 o;
    o.x = acc.x * inv + bb.x; o.y = acc.y * inv + bb.y;
    o.z = acc.z * inv + bb.z; o.w = acc.w * inv + bb.w;
    o.x = o.x > 0.f ? o.x : 0.f; o.y = o.y > 0.f ? o.y : 0.f;
    o.z = o.z > 0.f ? o.z : 0.f; o.w = o.w > 0.f ? o.w : 0.f;
    *(float4*)(out1 + (size_t)n * 256 + l * 4) = o;
}

// ---------------- GEMM2: h2[N,32] = out1[N,256] @ W2[256,32] ----------------
__global__ __launch_bounds__(256) void gemm2_kernel(const float* __restrict__ x,
                                                    const float* __restrict__ W,
                                                    float* __restrict__ h2) {
    __shared__ float xs[128 * 68];  // 128 rows x 64 K-chunk, stride 68
    __shared__ float wsh[64 * 32];  // 64 K x 32 cols
    int t = threadIdx.x;
    int rb = blockIdx.x * 128;
    int tx = t & 7, ty = t >> 3;
    float acc[4][4] = {};
    for (int kb = 0; kb < 256; kb += 64) {
        __syncthreads();
#pragma unroll
        for (int i = 0; i < 8; ++i) {
            int f = t + i * 256;     // 0..2047 float4 slots
            int row = f >> 4;        // 16 float4 per row
            int c4 = f & 15;
            float4 v = make_float4(0.f, 0.f, 0.f, 0.f);
            int gr = rb + row;
            if (gr < NNODES) v = *(const float4*)(x + gr * 256 + kb + c4 * 4);
            *(float4*)(xs + row * 68 + c4 * 4) = v;
        }
#pragma unroll
        for (int i = 0; i < 2; ++i) {
            int f = t + i * 256;     // 0..511 float4 slots
            int k = f >> 3;          // 8 float4 per row
            int c4 = f & 7;
            float4 v = *(const float4*)(W + (kb + k) * 32 + c4 * 4);
            *(float4*)(wsh + k * 32 + c4 * 4) = v;
        }
        __syncthreads();
#pragma unroll 8
        for (int kk = 0; kk < 64; ++kk) {
            float a0 = xs[(ty * 4 + 0) * 68 + kk];
            float a1 = xs[(ty * 4 + 1) * 68 + kk];
            float a2 = xs[(ty * 4 + 2) * 68 + kk];
            float a3 = xs[(ty * 4 + 3) * 68 + kk];
            float4 b = *(float4*)(wsh + kk * 32 + tx * 4);
            acc[0][0] += a0 * b.x; acc[0][1] += a0 * b.y; acc[0][2] += a0 * b.z; acc[0][3] += a0 * b.w;
            acc[1][0] += a1 * b.x; acc[1][1] += a1 * b.y; acc[1][2] += a1 * b.z; acc[1][3] += a1 * b.w;
            acc[2][0] += a2 * b.x; acc[2][1] += a2 * b.y; acc[2][2] += a2 * b.z; acc[2][3] += a2 * b.w;
            acc[3][0] += a3 * b.x; acc[3][1] += a3 * b.y; acc[3][2] += a3 * b.z; acc[3][3] += a3 * b.w;
        }
    }
#pragma unroll
    for (int i = 0; i < 4; ++i) {
        int gr = rb + ty * 4 + i;
        if (gr < NNODES) {
            float4 v = make_float4(acc[i][0], acc[i][1], acc[i][2], acc[i][3]);
            *(float4*)(h2 + gr * 32 + tx * 4) = v;
        }
    }
}

// ---------------- al2 ----------------
__global__ __launch_bounds__(256) void al2_kernel(const float* __restrict__ h2,
                                                  const float* __restrict__ a_src,
                                                  const float* __restrict__ a_dst,
                                                  float* __restrict__ al_s,
                                                  float* __restrict__ al_d) {
    int t = threadIdx.x;
    int l = t & 31;
    int n = blockIdx.x * 8 + (t >> 5);
    if (n >= NNODES) return;
    float v = h2[n * HID + l];
    float ps = v * a_src[l];
    float pd = v * a_dst[l];
    ps += __shfl_xor(ps, 1);  pd += __shfl_xor(pd, 1);
    ps += __shfl_xor(ps, 2);  pd += __shfl_xor(pd, 2);
    ps += __shfl_xor(ps, 4);  pd += __shfl_xor(pd, 4);
    ps += __shfl_xor(ps, 8);  pd += __shfl_xor(pd, 8);
    ps += __shfl_xor(ps, 16); pd += __shfl_xor(pd, 16);
    if (l == 0) {
        al_s[n] = ps;
        al_d[n] = pd;
    }
}

// ---------------- gather layer 2: per-node output, NO atomics ----------------
__global__ __launch_bounds__(256) void gather2_kernel(const float* __restrict__ h2,
                                                      const float* __restrict__ al_s,
                                                      const float* __restrict__ al_d,
                                                      const int* __restrict__ row_start,
                                                      const int* __restrict__ csr_src,
                                                      const float* __restrict__ b2,
                                                      float* __restrict__ out2) {
    int t = threadIdx.x;
    int c = t & 31;
    int n = blockIdx.x * 8 + (t >> 5);
    if (n >= NNODES) return;
    float ad = al_d[n];
    float p = __expf(leaky(al_s[n] + ad));
    float z = p;
    float acc = p * h2[n * HID + c];
    int beg = row_start[n];
    int end = (n + 1 < NNODES) ? row_start[n + 1] : NEDGES;
    for (int i = beg; i < end; ++i) {
        int s = csr_src[i];
        float pe = __expf(leaky(al_s[s] + ad));
        z += pe;
        acc += pe * h2[s * HID + c];
    }
    out2[n * HID + c] = acc / z + b2[c];
}

// ---------------- mean-pool: one block per graph, batch is sorted ----------------
__global__ __launch_bounds__(256) void pool_kernel(const float* __restrict__ out2,
                                                   const int* __restrict__ batch,
                                                   float* __restrict__ out) {
    __shared__ float red[256];
    int g = blockIdx.x;          // 0..63
    int t = threadIdx.x;
    int c = t & 31;
    int sub = t >> 5;            // 8 node-strided subgroups
    int beg, end;
    {
        int lo = 0, hi = NNODES;
        while (lo < hi) { int mid = (lo + hi) >> 1; if (batch[mid] < g) lo = mid + 1; else hi = mid; }
        beg = lo;
        lo = beg; hi = NNODES;
        while (lo < hi) { int mid = (lo + hi) >> 1; if (batch[mid] < g + 1) lo = mid + 1; else hi = mid; }
        end = lo;
    }
    float s = 0.f;
    for (int n = beg + sub; n < end; n += 8) s += out2[n * HID + c];
    red[t] = s;
    __syncthreads();
    if (t < 32) {
        float tot = 0.f;
#pragma unroll
        for (int k = 0; k < 8; ++k) tot += red[c + 32 * k];
        int cnt = end - beg;
        out[g * HID + c] = tot / (float)(cnt > 0 ? cnt : 1);
    }
}

extern "C" void kernel_launch(void* const* d_in, const int* in_sizes, int n_in,
                              void* d_out, int out_size, void* d_ws, size_t ws_size,
                              hipStream_t stream) {
    const float* x      = (const float*)d_in[0];
    const int*   ei     = (const int*)d_in[1];
    // d_in[2] = edge_attr (unused)
    const int*   batch  = (const int*)d_in[3];
    const float* W1     = (const float*)d_in[4];
    const float* a_src1 = (const float*)d_in[5];
    const float* a_dst1 = (const float*)d_in[6];
    const float* b1     = (const float*)d_in[7];
    const float* W2     = (const float*)d_in[8];
    const float* a_src2 = (const float*)d_in[9];
    const float* a_dst2 = (const float*)d_in[10];
    const float* b2     = (const float*)d_in[11];
    float* out = (float*)d_out;

    char* ws = (char*)d_ws;
    size_t off = 0;
    auto alloc = [&](size_t bytes) {
        size_t o = off;
        off = (off + bytes + 255) & ~(size_t)255;
        return o;
    };
    float* h1     = (float*)(ws + alloc((size_t)NNODES * 256 * 4));
    float* out1   = (float*)(ws + alloc((size_t)NNODES * 256 * 4));
    float* h2     = (float*)(ws + alloc((size_t)NNODES * HID * 4));
    float* out2   = (float*)(ws + alloc((size_t)NNODES * HID * 4));
    float* al_s1  = (float*)(ws + alloc((size_t)NNODES * HEADS * 4));
    float* al_d1  = (float*)(ws + alloc((size_t)NNODES * HEADS * 4));
    float* al_s2  = (float*)(ws + alloc((size_t)NNODES * 4));
    float* al_d2  = (float*)(ws + alloc((size_t)NNODES * 4));
    int*   deg    = (int*)(ws + alloc((size_t)NNODES * 4));
    int*   rowst  = (int*)(ws + alloc((size_t)NNODES * 4));
    int*   cursor = (int*)(ws + alloc((size_t)NNODES * 4));
    int*   bsums  = (int*)(ws + alloc(256 * 4));
    int*   boffs  = (int*)(ws + alloc(256 * 4));
    int*   csr    = (int*)(ws + alloc((size_t)NEDGES * 4));
    (void)ws_size;

    int nb_nodes = (NNODES + 255) / 256;      // 196
    int nb_edges = (NEDGES + 255) / 256;      // 3125

    zero_kernel<<<nb_nodes, 256, 0, stream>>>(deg);
    deg_kernel<<<nb_edges, 256, 0, stream>>>(ei, deg);
    scan_block<<<nb_nodes, 256, 0, stream>>>(deg, NNODES, rowst, bsums);
    scan_block<<<1, 256, 0, stream>>>(bsums, nb_nodes, boffs, (int*)nullptr);
    scan_add<<<nb_nodes, 256, 0, stream>>>(rowst, boffs, cursor);
    scatter_kernel<<<nb_edges, 256, 0, stream>>>(ei, cursor, csr);

    dim3 g1((NNODES + 63) / 64, 4);
    gemm1_kernel<<<g1, 256, 0, stream>>>(x, W1, h1);
    al1_kernel<<<(NNODES + 3) / 4, 256, 0, stream>>>(h1, a_src1, a_dst1, al_s1, al_d1);
    gather1_kernel<<<(NNODES + 3) / 4, 256, 0, stream>>>(h1, al_s1, al_d1, rowst, csr, b1, out1);

    gemm2_kernel<<<(NNODES + 127) / 128, 256, 0, stream>>>(out1, W2, h2);
    al2_kernel<<<(NNODES + 7) / 8, 256, 0, stream>>>(h2, a_src2, a_dst2, al_s2, al_d2);
    gather2_kernel<<<(NNODES + 7) / 8, 256, 0, stream>>>(h2, al_s2, al_d2, rowst, csr, b2, out2);
    pool_kernel<<<NG, 256, 0, stream>>>(out2, batch, out);
}

// Round 5
// 416.327 us; speedup vs baseline: 2.2726x; 1.2039x over previous
//
#include <hip/hip_runtime.h>
#include <hip/hip_bf16.h>

#define NNODES 50000
#define NEDGES 800000
#define FIN 128
#define HID 32
#define HEADS 8
#define NG 64
#define NEG_SLOPE 0.2f

static __device__ __forceinline__ float leaky(float x) {
    return x > 0.f ? x : NEG_SLOPE * x;
}
// bf16 helpers (RNE pack, cheap unpack)
static __device__ __forceinline__ unsigned short f2bf(float f) {
    unsigned int x = __float_as_uint(f);
    return (unsigned short)((x + 0x7FFFu + ((x >> 16) & 1u)) >> 16);
}
static __device__ __forceinline__ float bfl(unsigned int u) {   // low bf16 of dword
    return __uint_as_float(u << 16);
}
static __device__ __forceinline__ float bfh(unsigned int u) {   // high bf16 of dword
    return __uint_as_float(u & 0xFFFF0000u);
}

// ---------------- zero init ----------------
__global__ void zero_kernel(int* deg) {
    int i = blockIdx.x * 256 + threadIdx.x;
    if (i < NNODES) deg[i] = 0;
}

// ---------------- degree histogram ----------------
__global__ void deg_kernel(const int* __restrict__ ei, int* __restrict__ deg) {
    int e = blockIdx.x * 256 + threadIdx.x;
    if (e < NEDGES) {
        int d = ei[NEDGES + e];   // dst row
        atomicAdd(&deg[d], 1);
    }
}

// ---------------- block-wise exclusive scan ----------------
__global__ void scan_block(const int* __restrict__ in, int n, int* __restrict__ out_excl,
                           int* __restrict__ bsums) {
    __shared__ int s[256];
    int t = threadIdx.x;
    int i = blockIdx.x * 256 + t;
    int v = (i < n) ? in[i] : 0;
    s[t] = v;
    __syncthreads();
    for (int off = 1; off < 256; off <<= 1) {
        int x = (t >= off) ? s[t - off] : 0;
        __syncthreads();
        s[t] += x;
        __syncthreads();
    }
    if (i < n) out_excl[i] = s[t] - v;
    if (bsums && t == 255) bsums[blockIdx.x] = s[255];
}

__global__ void scan_add(int* __restrict__ row, const int* __restrict__ boffs,
                         int* __restrict__ cursor) {
    int i = blockIdx.x * 256 + threadIdx.x;
    if (i < NNODES) {
        int r = row[i] + boffs[blockIdx.x];
        row[i] = r;
        cursor[i] = r;
    }
}

// ---------------- scatter edges into CSR ----------------
__global__ void scatter_kernel(const int* __restrict__ ei, int* __restrict__ cursor,
                               int* __restrict__ csr_src) {
    int e = blockIdx.x * 256 + threadIdx.x;
    if (e < NEDGES) {
        int s = ei[e];
        int d = ei[NEDGES + e];
        int pos = atomicAdd(&cursor[d], 1);
        csr_src[pos] = s;
    }
}

// ---------------- GEMM1: h1b[N,256](bf16) = x[N,128] @ W1[128,256] ----------------
__global__ __launch_bounds__(256) void gemm1_kernel(const float* __restrict__ x,
                                                    const float* __restrict__ W,
                                                    unsigned short* __restrict__ h1b) {
    __shared__ float xs[64 * 132];   // 64 rows x 128 K, stride 132 (pad)
    __shared__ float wsh[128 * 64];  // 128 K x 64 cols
    int t = threadIdx.x;
    int rb = blockIdx.x * 64;
    int cb = blockIdx.y * 64;
#pragma unroll
    for (int i = 0; i < 8; ++i) {
        int f = t + i * 256;      // 0..2047
        int row = f >> 5;         // 32 float4 per row
        int c4 = f & 31;
        float4 v = make_float4(0.f, 0.f, 0.f, 0.f);
        int gr = rb + row;
        if (gr < NNODES) v = *(const float4*)(x + gr * FIN + c4 * 4);
        *(float4*)(xs + row * 132 + c4 * 4) = v;
    }
#pragma unroll
    for (int i = 0; i < 8; ++i) {
        int f = t + i * 256;      // 0..2047
        int k = f >> 4;           // 16 float4 per row
        int c4 = f & 15;
        float4 v = *(const float4*)(W + k * 256 + cb + c4 * 4);
        *(float4*)(wsh + k * 64 + c4 * 4) = v;
    }
    __syncthreads();
    int tx = t & 15, ty = t >> 4;
    float acc[4][4] = {};
#pragma unroll 8
    for (int k = 0; k < 128; ++k) {
        float a0 = xs[(ty * 4 + 0) * 132 + k];
        float a1 = xs[(ty * 4 + 1) * 132 + k];
        float a2 = xs[(ty * 4 + 2) * 132 + k];
        float a3 = xs[(ty * 4 + 3) * 132 + k];
        float4 b = *(float4*)(wsh + k * 64 + tx * 4);
        acc[0][0] += a0 * b.x; acc[0][1] += a0 * b.y; acc[0][2] += a0 * b.z; acc[0][3] += a0 * b.w;
        acc[1][0] += a1 * b.x; acc[1][1] += a1 * b.y; acc[1][2] += a1 * b.z; acc[1][3] += a1 * b.w;
        acc[2][0] += a2 * b.x; acc[2][1] += a2 * b.y; acc[2][2] += a2 * b.z; acc[2][3] += a2 * b.w;
        acc[3][0] += a3 * b.x; acc[3][1] += a3 * b.y; acc[3][2] += a3 * b.z; acc[3][3] += a3 * b.w;
    }
#pragma unroll
    for (int i = 0; i < 4; ++i) {
        int gr = rb + ty * 4 + i;
        if (gr < NNODES) {
            ushort4 s;
            s.x = f2bf(acc[i][0]); s.y = f2bf(acc[i][1]);
            s.z = f2bf(acc[i][2]); s.w = f2bf(acc[i][3]);
            *(ushort4*)(h1b + (size_t)gr * 256 + cb + tx * 4) = s;
        }
    }
}

// ---------------- al1: per-node attention logits (bf16 h1) ----------------
__global__ __launch_bounds__(256) void al1_kernel(const unsigned short* __restrict__ h1b,
                                                  const float* __restrict__ a_src,
                                                  const float* __restrict__ a_dst,
                                                  float* __restrict__ al_s,
                                                  float* __restrict__ al_d) {
    int t = threadIdx.x;
    int l = t & 63;
    int n = blockIdx.x * 4 + (t >> 6);
    if (n >= NNODES) return;
    uint2 uv = *(const uint2*)(h1b + (size_t)n * 256 + l * 4);
    float v0 = bfl(uv.x), v1 = bfh(uv.x), v2 = bfl(uv.y), v3 = bfh(uv.y);
    float4 as = *(const float4*)(a_src + l * 4);
    float4 ad = *(const float4*)(a_dst + l * 4);
    float ps = v0 * as.x + v1 * as.y + v2 * as.z + v3 * as.w;
    float pd = v0 * ad.x + v1 * ad.y + v2 * ad.z + v3 * ad.w;
    ps += __shfl_xor(ps, 1); pd += __shfl_xor(pd, 1);
    ps += __shfl_xor(ps, 2); pd += __shfl_xor(pd, 2);
    ps += __shfl_xor(ps, 4); pd += __shfl_xor(pd, 4);
    if ((l & 7) == 0) {
        int h = l >> 3;
        al_s[n * HEADS + h] = ps;
        al_d[n * HEADS + h] = pd;
    }
}

// ---------------- gather layer 1: 32 lanes/node (2 nodes/wave), bf16 rows ----------------
// lane q (0..31) covers cols 8q..8q+7 (head q>>2). Chunks of 4 edges staged
// across half-wave: lane q holds (edge q>>3, head q&7). shfl broadcast, no LDS.
__global__ __launch_bounds__(256) void gather1_kernel(const unsigned short* __restrict__ h1b,
                                                      const float* __restrict__ al_s,
                                                      const float* __restrict__ al_d,
                                                      const int* __restrict__ row_start,
                                                      const int* __restrict__ csr_src,
                                                      const float* __restrict__ b1,
                                                      float* __restrict__ out1) {
    int t = threadIdx.x;
    int l = t & 63;
    int q = l & 31;
    int base = l & 32;            // half-wave base for shfl
    int n = blockIdx.x * 8 + (t >> 5);
    int e_st = q >> 3;            // staged edge slot 0..3
    int h_st = q & 7;             // staged head
    int h_f  = q >> 2;            // fma-phase head (cols 8q..8q+7)
    float ad_st = al_d[n * HEADS + h_st];

    // self loop
    float p = __expf(leaky(al_s[n * HEADS + h_f] + al_d[n * HEADS + h_f]));
    float z = p;
    float acc[8];
    {
        uint4 v = *(const uint4*)(h1b + (size_t)n * 256 + q * 8);
        acc[0] = p * bfl(v.x); acc[1] = p * bfh(v.x);
        acc[2] = p * bfl(v.y); acc[3] = p * bfh(v.y);
        acc[4] = p * bfl(v.z); acc[5] = p * bfh(v.z);
        acc[6] = p * bfl(v.w); acc[7] = p * bfh(v.w);
    }

    int beg = row_start[n];
    int end = (n + 1 < NNODES) ? row_start[n + 1] : NEDGES;
    for (int i = beg; i < end; i += 4) {
        int rem = end - i;
        int src4 = n;             // padded slots: hot self row, pe = 0
        float pe4 = 0.f;
        if (e_st < rem) {
            src4 = csr_src[i + e_st];
            pe4 = __expf(leaky(al_s[src4 * HEADS + h_st] + ad_st));
        }
#pragma unroll
        for (int j = 0; j < 4; ++j) {
            int   sj  = __shfl(src4, base + j * 8);
            float pej = __shfl(pe4, base + j * 8 + h_f);
            uint4 v = *(const uint4*)(h1b + (size_t)sj * 256 + q * 8);
            z += pej;
            acc[0] += pej * bfl(v.x); acc[1] += pej * bfh(v.x);
            acc[2] += pej * bfl(v.y); acc[3] += pej * bfh(v.y);
            acc[4] += pej * bfl(v.z); acc[5] += pej * bfh(v.z);
            acc[6] += pej * bfl(v.w); acc[7] += pej * bfh(v.w);
        }
    }
    float inv = 1.0f / z;
    float4 b0 = *(const float4*)(b1 + q * 8);
    float4 b2 = *(const float4*)(b1 + q * 8 + 4);
    float4 o0, o1;
    o0.x = acc[0] * inv + b0.x; o0.y = acc[1] * inv + b0.y;
    o0.z = acc[2] * inv + b0.z; o0.w = acc[3] * inv + b0.w;
    o1.x = acc[4] * inv + b2.x; o1.y = acc[5] * inv + b2.y;
    o1.z = acc[6] * inv + b2.z; o1.w = acc[7] * inv + b2.w;
    o0.x = o0.x > 0.f ? o0.x : 0.f; o0.y = o0.y > 0.f ? o0.y : 0.f;
    o0.z = o0.z > 0.f ? o0.z : 0.f; o0.w = o0.w > 0.f ? o0.w : 0.f;
    o1.x = o1.x > 0.f ? o1.x : 0.f; o1.y = o1.y > 0.f ? o1.y : 0.f;
    o1.z = o1.z > 0.f ? o1.z : 0.f; o1.w = o1.w > 0.f ? o1.w : 0.f;
    *(float4*)(out1 + (size_t)n * 256 + q * 8) = o0;
    *(float4*)(out1 + (size_t)n * 256 + q * 8 + 4) = o1;
}

// ---------------- GEMM2: h2[N,32] = out1[N,256] @ W2[256,32] ----------------
__global__ __launch_bounds__(256) void gemm2_kernel(const float* __restrict__ x,
                                                    const float* __restrict__ W,
                                                    float* __restrict__ h2) {
    __shared__ float xs[128 * 68];  // 128 rows x 64 K-chunk, stride 68
    __shared__ float wsh[64 * 32];  // 64 K x 32 cols
    int t = threadIdx.x;
    int rb = blockIdx.x * 128;
    int tx = t & 7, ty = t >> 3;
    float acc[4][4] = {};
    for (int kb = 0; kb < 256; kb += 64) {
        __syncthreads();
#pragma unroll
        for (int i = 0; i < 8; ++i) {
            int f = t + i * 256;     // 0..2047 float4 slots
            int row = f >> 4;        // 16 float4 per row
            int c4 = f & 15;
            float4 v = make_float4(0.f, 0.f, 0.f, 0.f);
            int gr = rb + row;
            if (gr < NNODES) v = *(const float4*)(x + gr * 256 + kb + c4 * 4);
            *(float4*)(xs + row * 68 + c4 * 4) = v;
        }
#pragma unroll
        for (int i = 0; i < 2; ++i) {
            int f = t + i * 256;     // 0..511 float4 slots
            int k = f >> 3;          // 8 float4 per row
            int c4 = f & 7;
            float4 v = *(const float4*)(W + (kb + k) * 32 + c4 * 4);
            *(float4*)(wsh + k * 32 + c4 * 4) = v;
        }
        __syncthreads();
#pragma unroll 8
        for (int kk = 0; kk < 64; ++kk) {
            float a0 = xs[(ty * 4 + 0) * 68 + kk];
            float a1 = xs[(ty * 4 + 1) * 68 + kk];
            float a2 = xs[(ty * 4 + 2) * 68 + kk];
            float a3 = xs[(ty * 4 + 3) * 68 + kk];
            float4 b = *(float4*)(wsh + kk * 32 + tx * 4);
            acc[0][0] += a0 * b.x; acc[0][1] += a0 * b.y; acc[0][2] += a0 * b.z; acc[0][3] += a0 * b.w;
            acc[1][0] += a1 * b.x; acc[1][1] += a1 * b.y; acc[1][2] += a1 * b.z; acc[1][3] += a1 * b.w;
            acc[2][0] += a2 * b.x; acc[2][1] += a2 * b.y; acc[2][2] += a2 * b.z; acc[2][3] += a2 * b.w;
            acc[3][0] += a3 * b.x; acc[3][1] += a3 * b.y; acc[3][2] += a3 * b.z; acc[3][3] += a3 * b.w;
        }
    }
#pragma unroll
    for (int i = 0; i < 4; ++i) {
        int gr = rb + ty * 4 + i;
        if (gr < NNODES) {
            float4 v = make_float4(acc[i][0], acc[i][1], acc[i][2], acc[i][3]);
            *(float4*)(h2 + gr * 32 + tx * 4) = v;
        }
    }
}

// ---------------- al2 ----------------
__global__ __launch_bounds__(256) void al2_kernel(const float* __restrict__ h2,
                                                  const float* __restrict__ a_src,
                                                  const float* __restrict__ a_dst,
                                                  float* __restrict__ al_s,
                                                  float* __restrict__ al_d) {
    int t = threadIdx.x;
    int l = t & 31;
    int n = blockIdx.x * 8 + (t >> 5);
    if (n >= NNODES) return;
    float v = h2[n * HID + l];
    float ps = v * a_src[l];
    float pd = v * a_dst[l];
    ps += __shfl_xor(ps, 1);  pd += __shfl_xor(pd, 1);
    ps += __shfl_xor(ps, 2);  pd += __shfl_xor(pd, 2);
    ps += __shfl_xor(ps, 4);  pd += __shfl_xor(pd, 4);
    ps += __shfl_xor(ps, 8);  pd += __shfl_xor(pd, 8);
    ps += __shfl_xor(ps, 16); pd += __shfl_xor(pd, 16);
    if (l == 0) {
        al_s[n] = ps;
        al_d[n] = pd;
    }
}

// ---------------- gather layer 2: staged exp + shfl broadcast, no atomics ----------------
// 32 lanes/node (2 nodes/wave); chunks of 32 edges, 1 exp per edge.
__global__ __launch_bounds__(256) void gather2_kernel(const float* __restrict__ h2,
                                                      const float* __restrict__ al_s,
                                                      const float* __restrict__ al_d,
                                                      const int* __restrict__ row_start,
                                                      const int* __restrict__ csr_src,
                                                      const float* __restrict__ b2,
                                                      float* __restrict__ out2) {
    int t = threadIdx.x;
    int l = t & 63;
    int c = l & 31;
    int base = l & 32;
    int n = blockIdx.x * 8 + (t >> 5);
    float ad = al_d[n];
    float p = __expf(leaky(al_s[n] + ad));
    float z = p;
    float acc = p * h2[n * HID + c];
    int beg = row_start[n];
    int end = (n + 1 < NNODES) ? row_start[n + 1] : NEDGES;
    for (int i = beg; i < end; i += 32) {
        int rem = end - i;
        int src = n;
        float pe = 0.f;
        if (c < rem) {
            src = csr_src[i + c];
            pe = __expf(leaky(al_s[src] + ad));
        }
        int m = rem < 32 ? rem : 32;
        for (int j = 0; j < m; ++j) {
            int   sj  = __shfl(src, base + j);
            float pej = __shfl(pe, base + j);
            z += pej;
            acc += pej * h2[sj * HID + c];
        }
    }
    out2[n * HID + c] = acc / z + b2[c];
}

// ---------------- mean-pool: one block per graph, batch is sorted ----------------
__global__ __launch_bounds__(256) void pool_kernel(const float* __restrict__ out2,
                                                   const int* __restrict__ batch,
                                                   float* __restrict__ out) {
    __shared__ float red[256];
    int g = blockIdx.x;          // 0..63
    int t = threadIdx.x;
    int c = t & 31;
    int sub = t >> 5;            // 8 node-strided subgroups
    int beg, end;
    {
        int lo = 0, hi = NNODES;
        while (lo < hi) { int mid = (lo + hi) >> 1; if (batch[mid] < g) lo = mid + 1; else hi = mid; }
        beg = lo;
        lo = beg; hi = NNODES;
        while (lo < hi) { int mid = (lo + hi) >> 1; if (batch[mid] < g + 1) lo = mid + 1; else hi = mid; }
        end = lo;
    }
    float s = 0.f;
    for (int n = beg + sub; n < end; n += 8) s += out2[n * HID + c];
    red[t] = s;
    __syncthreads();
    if (t < 32) {
        float tot = 0.f;
#pragma unroll
        for (int k = 0; k < 8; ++k) tot += red[c + 32 * k];
        int cnt = end - beg;
        out[g * HID + c] = tot / (float)(cnt > 0 ? cnt : 1);
    }
}

extern "C" void kernel_launch(void* const* d_in, const int* in_sizes, int n_in,
                              void* d_out, int out_size, void* d_ws, size_t ws_size,
                              hipStream_t stream) {
    const float* x      = (const float*)d_in[0];
    const int*   ei     = (const int*)d_in[1];
    // d_in[2] = edge_attr (unused)
    const int*   batch  = (const int*)d_in[3];
    const float* W1     = (const float*)d_in[4];
    const float* a_src1 = (const float*)d_in[5];
    const float* a_dst1 = (const float*)d_in[6];
    const float* b1     = (const float*)d_in[7];
    const float* W2     = (const float*)d_in[8];
    const float* a_src2 = (const float*)d_in[9];
    const float* a_dst2 = (const float*)d_in[10];
    const float* b2     = (const float*)d_in[11];
    float* out = (float*)d_out;

    char* ws = (char*)d_ws;
    size_t off = 0;
    auto alloc = [&](size_t bytes) {
        size_t o = off;
        off = (off + bytes + 255) & ~(size_t)255;
        return o;
    };
    unsigned short* h1b = (unsigned short*)(ws + alloc((size_t)NNODES * 256 * 2));
    float* out1   = (float*)(ws + alloc((size_t)NNODES * 256 * 4));
    float* h2     = (float*)(ws + alloc((size_t)NNODES * HID * 4));
    float* out2   = (float*)(ws + alloc((size_t)NNODES * HID * 4));
    float* al_s1  = (float*)(ws + alloc((size_t)NNODES * HEADS * 4));
    float* al_d1  = (float*)(ws + alloc((size_t)NNODES * HEADS * 4));
    float* al_s2  = (float*)(ws + alloc((size_t)NNODES * 4));
    float* al_d2  = (float*)(ws + alloc((size_t)NNODES * 4));
    int*   deg    = (int*)(ws + alloc((size_t)NNODES * 4));
    int*   rowst  = (int*)(ws + alloc((size_t)NNODES * 4));
    int*   cursor = (int*)(ws + alloc((size_t)NNODES * 4));
    int*   bsums  = (int*)(ws + alloc(256 * 4));
    int*   boffs  = (int*)(ws + alloc(256 * 4));
    int*   csr    = (int*)(ws + alloc((size_t)NEDGES * 4));
    (void)ws_size;

    int nb_nodes = (NNODES + 255) / 256;      // 196
    int nb_edges = (NEDGES + 255) / 256;      // 3125

    zero_kernel<<<nb_nodes, 256, 0, stream>>>(deg);
    deg_kernel<<<nb_edges, 256, 0, stream>>>(ei, deg);
    scan_block<<<nb_nodes, 256, 0, stream>>>(deg, NNODES, rowst, bsums);
    scan_block<<<1, 256, 0, stream>>>(bsums, nb_nodes, boffs, (int*)nullptr);
    scan_add<<<nb_nodes, 256, 0, stream>>>(rowst, boffs, cursor);
    scatter_kernel<<<nb_edges, 256, 0, stream>>>(ei, cursor, csr);

    dim3 g1((NNODES + 63) / 64, 4);
    gemm1_kernel<<<g1, 256, 0, stream>>>(x, W1, h1b);
    al1_kernel<<<(NNODES + 3) / 4, 256, 0, stream>>>(h1b, a_src1, a_dst1, al_s1, al_d1);
    gather1_kernel<<<NNODES / 8, 256, 0, stream>>>(h1b, al_s1, al_d1, rowst, csr, b1, out1);

    gemm2_kernel<<<(NNODES + 127) / 128, 256, 0, stream>>>(out1, W2, h2);
    al2_kernel<<<(NNODES + 7) / 8, 256, 0, stream>>>(h2, a_src2, a_dst2, al_s2, al_d2);
    gather2_kernel<<<NNODES / 8, 256, 0, stream>>>(h2, al_s2, al_d2, rowst, csr, b2, out2);
    pool_kernel<<<NG, 256, 0, stream>>>(out2, batch, out);
}

// Round 6
// 381.327 us; speedup vs baseline: 2.4812x; 1.0918x over previous
//
#include <hip/hip_runtime.h>
#include <hip/hip_bf16.h>

#define NNODES 50000
#define NEDGES 800000
#define FIN 128
#define HID 32
#define HEADS 8
#define NG 64
#define NEG_SLOPE 0.2f

using bf16x8 = __attribute__((ext_vector_type(8))) short;   // 8 bf16 (4 VGPRs)
using f32x4  = __attribute__((ext_vector_type(4))) float;   // MFMA acc

static __device__ __forceinline__ float leaky(float x) {
    return x > 0.f ? x : NEG_SLOPE * x;
}
// bf16 helpers (RNE pack, cheap unpack)
static __device__ __forceinline__ unsigned short f2bf(float f) {
    unsigned int x = __float_as_uint(f);
    return (unsigned short)((x + 0x7FFFu + ((x >> 16) & 1u)) >> 16);
}
static __device__ __forceinline__ float bfl(unsigned int u) {
    return __uint_as_float(u << 16);
}
static __device__ __forceinline__ float bfh(unsigned int u) {
    return __uint_as_float(u & 0xFFFF0000u);
}

// ---------------- zero init ----------------
__global__ void zero_kernel(int* deg) {
    int i = blockIdx.x * 256 + threadIdx.x;
    if (i < NNODES) deg[i] = 0;
}

// ---------------- degree histogram ----------------
__global__ void deg_kernel(const int* __restrict__ ei, int* __restrict__ deg) {
    int e = blockIdx.x * 256 + threadIdx.x;
    if (e < NEDGES) {
        int d = ei[NEDGES + e];
        atomicAdd(&deg[d], 1);
    }
}

// ---------------- block-wise exclusive scan ----------------
__global__ void scan_block(const int* __restrict__ in, int n, int* __restrict__ out_excl,
                           int* __restrict__ bsums) {
    __shared__ int s[256];
    int t = threadIdx.x;
    int i = blockIdx.x * 256 + t;
    int v = (i < n) ? in[i] : 0;
    s[t] = v;
    __syncthreads();
    for (int off = 1; off < 256; off <<= 1) {
        int x = (t >= off) ? s[t - off] : 0;
        __syncthreads();
        s[t] += x;
        __syncthreads();
    }
    if (i < n) out_excl[i] = s[t] - v;
    if (bsums && t == 255) bsums[blockIdx.x] = s[255];
}

__global__ void scan_add(int* __restrict__ row, const int* __restrict__ boffs,
                         int* __restrict__ cursor) {
    int i = blockIdx.x * 256 + threadIdx.x;
    if (i < NNODES) {
        int r = row[i] + boffs[blockIdx.x];
        row[i] = r;
        cursor[i] = r;
    }
}

// ---------------- scatter edges into CSR ----------------
__global__ void scatter_kernel(const int* __restrict__ ei, int* __restrict__ cursor,
                               int* __restrict__ csr_src) {
    int e = blockIdx.x * 256 + threadIdx.x;
    if (e < NEDGES) {
        int s = ei[e];
        int d = ei[NEDGES + e];
        int pos = atomicAdd(&cursor[d], 1);
        csr_src[pos] = s;
    }
}

// ---------------- W1 pre-swizzle into B-fragment order (bf16) ----------------
// w1s[((ct*4 + ks)*64 + lane)*8 + j] = bf16( W1[ ks*32 + (lane>>4)*8 + j ][ ct*16 + (lane&15) ] )
__global__ void w1_swizzle_kernel(const float* __restrict__ W, unsigned short* __restrict__ w1s) {
    int idx = blockIdx.x * 256 + threadIdx.x;   // 0..32767
    if (idx >= 16 * 4 * 64 * 8) return;
    int j    = idx & 7;
    int lane = (idx >> 3) & 63;
    int ks   = (idx >> 9) & 3;
    int ct   = idx >> 11;
    int k = ks * 32 + (lane >> 4) * 8 + j;
    int n = ct * 16 + (lane & 15);
    w1s[idx] = f2bf(W[k * 256 + n]);
}

// ---------------- GEMM1 via MFMA: h1b[N,256](bf16) = x[N,128] @ W1 ----------------
// 4 waves/block; wave w owns cols w*64..w*64+63 (4 col-tiles), B-frags in registers.
// Block covers 64 rows (4 row-groups of 16). Epilogue transposes via per-wave LDS.
__global__ __launch_bounds__(256) void gemm1_mfma_kernel(const float* __restrict__ x,
                                                         const unsigned short* __restrict__ w1s,
                                                         unsigned short* __restrict__ h1b) {
    __shared__ unsigned short lds[4][16 * 64];   // 2 KB per wave
    int t = threadIdx.x;
    int w = t >> 6;
    int l = t & 63;
    int lane16 = l & 15, quad = l >> 4;

    // B-fragments: 4 col-tiles x 4 k-steps, one 16B load each (L2-hot, 64 KB total)
    bf16x8 bf[4][4];
    const bf16x8* wp = (const bf16x8*)w1s;
#pragma unroll
    for (int ct = 0; ct < 4; ++ct)
#pragma unroll
        for (int ks = 0; ks < 4; ++ks)
            bf[ct][ks] = wp[((w * 4 + ct) * 4 + ks) * 64 + l];

    int rbase = blockIdx.x * 64;
    for (int rg = 0; rg < 4; ++rg) {
        int row0 = rbase + rg * 16;
        int r = row0 + lane16;
        int r_eff = r < NNODES ? r : NNODES - 1;   // clamp reads; store guarded
        // A-fragments: A[m=lane16][k=ks*32+quad*8+j] -> 32B contiguous fp32, pack to bf16
        bf16x8 af[4];
#pragma unroll
        for (int ks = 0; ks < 4; ++ks) {
            const float* ap = x + (size_t)r_eff * FIN + ks * 32 + quad * 8;
            float4 a0 = *(const float4*)ap;
            float4 a1 = *(const float4*)(ap + 4);
            bf16x8 v;
            v[0] = (short)f2bf(a0.x); v[1] = (short)f2bf(a0.y);
            v[2] = (short)f2bf(a0.z); v[3] = (short)f2bf(a0.w);
            v[4] = (short)f2bf(a1.x); v[5] = (short)f2bf(a1.y);
            v[6] = (short)f2bf(a1.z); v[7] = (short)f2bf(a1.w);
            af[ks] = v;
        }
        f32x4 acc[4];
#pragma unroll
        for (int ct = 0; ct < 4; ++ct) acc[ct] = (f32x4){0.f, 0.f, 0.f, 0.f};
#pragma unroll
        for (int ks = 0; ks < 4; ++ks)
#pragma unroll
            for (int ct = 0; ct < 4; ++ct)
                acc[ct] = __builtin_amdgcn_mfma_f32_16x16x32_bf16(af[ks], bf[ct][ks], acc[ct], 0, 0, 0);
        // epilogue: C/D is col=lane16, row=quad*4+reg -> LDS transpose (wave-private chunk)
        unsigned short* lw = lds[w];
#pragma unroll
        for (int ct = 0; ct < 4; ++ct)
#pragma unroll
            for (int reg = 0; reg < 4; ++reg)
                lw[(quad * 4 + reg) * 64 + ct * 16 + lane16] = f2bf(acc[ct][reg]);
        // wave-synchronous DS ordering: same-wave read-after-write is in-order
        int row_l = l >> 2;
        int ch = l & 3;
        int gr = row0 + row_l;
        if (gr < NNODES) {
            const uint4* srcp = (const uint4*)(lw + row_l * 64 + ch * 16);
            uint4 d0 = srcp[0];
            uint4 d1 = srcp[1];
            uint4* dst = (uint4*)(h1b + (size_t)gr * 256 + w * 64 + ch * 16);
            dst[0] = d0;
            dst[1] = d1;
        }
    }
}

// ---------------- al1: per-node attention logits (bf16 h1) ----------------
__global__ __launch_bounds__(256) void al1_kernel(const unsigned short* __restrict__ h1b,
                                                  const float* __restrict__ a_src,
                                                  const float* __restrict__ a_dst,
                                                  float* __restrict__ al_s,
                                                  float* __restrict__ al_d) {
    int t = threadIdx.x;
    int l = t & 63;
    int n = blockIdx.x * 4 + (t >> 6);
    if (n >= NNODES) return;
    uint2 uv = *(const uint2*)(h1b + (size_t)n * 256 + l * 4);
    float v0 = bfl(uv.x), v1 = bfh(uv.x), v2 = bfl(uv.y), v3 = bfh(uv.y);
    float4 as = *(const float4*)(a_src + l * 4);
    float4 ad = *(const float4*)(a_dst + l * 4);
    float ps = v0 * as.x + v1 * as.y + v2 * as.z + v3 * as.w;
    float pd = v0 * ad.x + v1 * ad.y + v2 * ad.z + v3 * ad.w;
    ps += __shfl_xor(ps, 1); pd += __shfl_xor(pd, 1);
    ps += __shfl_xor(ps, 2); pd += __shfl_xor(pd, 2);
    ps += __shfl_xor(ps, 4); pd += __shfl_xor(pd, 4);
    if ((l & 7) == 0) {
        int h = l >> 3;
        al_s[n * HEADS + h] = ps;
        al_d[n * HEADS + h] = pd;
    }
}

// ---------------- gather layer 1: 32 lanes/node (2 nodes/wave), bf16 rows ----------------
__global__ __launch_bounds__(256) void gather1_kernel(const unsigned short* __restrict__ h1b,
                                                      const float* __restrict__ al_s,
                                                      const float* __restrict__ al_d,
                                                      const int* __restrict__ row_start,
                                                      const int* __restrict__ csr_src,
                                                      const float* __restrict__ b1,
                                                      float* __restrict__ out1) {
    int t = threadIdx.x;
    int l = t & 63;
    int q = l & 31;
    int base = l & 32;
    int n = blockIdx.x * 8 + (t >> 5);
    int e_st = q >> 3;
    int h_st = q & 7;
    int h_f  = q >> 2;
    float ad_st = al_d[n * HEADS + h_st];

    float p = __expf(leaky(al_s[n * HEADS + h_f] + al_d[n * HEADS + h_f]));
    float z = p;
    float acc[8];
    {
        uint4 v = *(const uint4*)(h1b + (size_t)n * 256 + q * 8);
        acc[0] = p * bfl(v.x); acc[1] = p * bfh(v.x);
        acc[2] = p * bfl(v.y); acc[3] = p * bfh(v.y);
        acc[4] = p * bfl(v.z); acc[5] = p * bfh(v.z);
        acc[6] = p * bfl(v.w); acc[7] = p * bfh(v.w);
    }

    int beg = row_start[n];
    int end = (n + 1 < NNODES) ? row_start[n + 1] : NEDGES;
    for (int i = beg; i < end; i += 4) {
        int rem = end - i;
        int src4 = n;
        float pe4 = 0.f;
        if (e_st < rem) {
            src4 = csr_src[i + e_st];
            pe4 = __expf(leaky(al_s[src4 * HEADS + h_st] + ad_st));
        }
#pragma unroll
        for (int j = 0; j < 4; ++j) {
            int   sj  = __shfl(src4, base + j * 8);
            float pej = __shfl(pe4, base + j * 8 + h_f);
            uint4 v = *(const uint4*)(h1b + (size_t)sj * 256 + q * 8);
            z += pej;
            acc[0] += pej * bfl(v.x); acc[1] += pej * bfh(v.x);
            acc[2] += pej * bfl(v.y); acc[3] += pej * bfh(v.y);
            acc[4] += pej * bfl(v.z); acc[5] += pej * bfh(v.z);
            acc[6] += pej * bfl(v.w); acc[7] += pej * bfh(v.w);
        }
    }
    float inv = 1.0f / z;
    float4 b0 = *(const float4*)(b1 + q * 8);
    float4 b2 = *(const float4*)(b1 + q * 8 + 4);
    float4 o0, o1;
    o0.x = acc[0] * inv + b0.x; o0.y = acc[1] * inv + b0.y;
    o0.z = acc[2] * inv + b0.z; o0.w = acc[3] * inv + b0.w;
    o1.x = acc[4] * inv + b2.x; o1.y = acc[5] * inv + b2.y;
    o1.z = acc[6] * inv + b2.z; o1.w = acc[7] * inv + b2.w;
    o0.x = o0.x > 0.f ? o0.x : 0.f; o0.y = o0.y > 0.f ? o0.y : 0.f;
    o0.z = o0.z > 0.f ? o0.z : 0.f; o0.w = o0.w > 0.f ? o0.w : 0.f;
    o1.x = o1.x > 0.f ? o1.x : 0.f; o1.y = o1.y > 0.f ? o1.y : 0.f;
    o1.z = o1.z > 0.f ? o1.z : 0.f; o1.w = o1.w > 0.f ? o1.w : 0.f;
    *(float4*)(out1 + (size_t)n * 256 + q * 8) = o0;
    *(float4*)(out1 + (size_t)n * 256 + q * 8 + 4) = o1;
}

// ---------------- GEMM2: h2[N,32] = out1[N,256] @ W2[256,32] ----------------
__global__ __launch_bounds__(256) void gemm2_kernel(const float* __restrict__ x,
                                                    const float* __restrict__ W,
                                                    float* __restrict__ h2) {
    __shared__ float xs[128 * 68];
    __shared__ float wsh[64 * 32];
    int t = threadIdx.x;
    int rb = blockIdx.x * 128;
    int tx = t & 7, ty = t >> 3;
    float acc[4][4] = {};
    for (int kb = 0; kb < 256; kb += 64) {
        __syncthreads();
#pragma unroll
        for (int i = 0; i < 8; ++i) {
            int f = t + i * 256;
            int row = f >> 4;
            int c4 = f & 15;
            float4 v = make_float4(0.f, 0.f, 0.f, 0.f);
            int gr = rb + row;
            if (gr < NNODES) v = *(const float4*)(x + gr * 256 + kb + c4 * 4);
            *(float4*)(xs + row * 68 + c4 * 4) = v;
        }
#pragma unroll
        for (int i = 0; i < 2; ++i) {
            int f = t + i * 256;
            int k = f >> 3;
            int c4 = f & 7;
            float4 v = *(const float4*)(W + (kb + k) * 32 + c4 * 4);
            *(float4*)(wsh + k * 32 + c4 * 4) = v;
        }
        __syncthreads();
#pragma unroll 8
        for (int kk = 0; kk < 64; ++kk) {
            float a0 = xs[(ty * 4 + 0) * 68 + kk];
            float a1 = xs[(ty * 4 + 1) * 68 + kk];
            float a2 = xs[(ty * 4 + 2) * 68 + kk];
            float a3 = xs[(ty * 4 + 3) * 68 + kk];
            float4 b = *(float4*)(wsh + kk * 32 + tx * 4);
            acc[0][0] += a0 * b.x; acc[0][1] += a0 * b.y; acc[0][2] += a0 * b.z; acc[0][3] += a0 * b.w;
            acc[1][0] += a1 * b.x; acc[1][1] += a1 * b.y; acc[1][2] += a1 * b.z; acc[1][3] += a1 * b.w;
            acc[2][0] += a2 * b.x; acc[2][1] += a2 * b.y; acc[2][2] += a2 * b.z; acc[2][3] += a2 * b.w;
            acc[3][0] += a3 * b.x; acc[3][1] += a3 * b.y; acc[3][2] += a3 * b.z; acc[3][3] += a3 * b.w;
        }
    }
#pragma unroll
    for (int i = 0; i < 4; ++i) {
        int gr = rb + ty * 4 + i;
        if (gr < NNODES) {
            float4 v = make_float4(acc[i][0], acc[i][1], acc[i][2], acc[i][3]);
            *(float4*)(h2 + gr * 32 + tx * 4) = v;
        }
    }
}

// ---------------- al2 ----------------
__global__ __launch_bounds__(256) void al2_kernel(const float* __restrict__ h2,
                                                  const float* __restrict__ a_src,
                                                  const float* __restrict__ a_dst,
                                                  float* __restrict__ al_s,
                                                  float* __restrict__ al_d) {
    int t = threadIdx.x;
    int l = t & 31;
    int n = blockIdx.x * 8 + (t >> 5);
    if (n >= NNODES) return;
    float v = h2[n * HID + l];
    float ps = v * a_src[l];
    float pd = v * a_dst[l];
    ps += __shfl_xor(ps, 1);  pd += __shfl_xor(pd, 1);
    ps += __shfl_xor(ps, 2);  pd += __shfl_xor(pd, 2);
    ps += __shfl_xor(ps, 4);  pd += __shfl_xor(pd, 4);
    ps += __shfl_xor(ps, 8);  pd += __shfl_xor(pd, 8);
    ps += __shfl_xor(ps, 16); pd += __shfl_xor(pd, 16);
    if (l == 0) {
        al_s[n] = ps;
        al_d[n] = pd;
    }
}

// ---------------- gather layer 2: staged exp + shfl broadcast, no atomics ----------------
__global__ __launch_bounds__(256) void gather2_kernel(const float* __restrict__ h2,
                                                      const float* __restrict__ al_s,
                                                      const float* __restrict__ al_d,
                                                      const int* __restrict__ row_start,
                                                      const int* __restrict__ csr_src,
                                                      const float* __restrict__ b2,
                                                      float* __restrict__ out2) {
    int t = threadIdx.x;
    int l = t & 63;
    int c = l & 31;
    int base = l & 32;
    int n = blockIdx.x * 8 + (t >> 5);
    float ad = al_d[n];
    float p = __expf(leaky(al_s[n] + ad));
    float z = p;
    float acc = p * h2[n * HID + c];
    int beg = row_start[n];
    int end = (n + 1 < NNODES) ? row_start[n + 1] : NEDGES;
    for (int i = beg; i < end; i += 32) {
        int rem = end - i;
        int src = n;
        float pe = 0.f;
        if (c < rem) {
            src = csr_src[i + c];
            pe = __expf(leaky(al_s[src] + ad));
        }
        int m = rem < 32 ? rem : 32;
        for (int j = 0; j < m; ++j) {
            int   sj  = __shfl(src, base + j);
            float pej = __shfl(pe, base + j);
            z += pej;
            acc += pej * h2[sj * HID + c];
        }
    }
    out2[n * HID + c] = acc / z + b2[c];
}

// ---------------- mean-pool: one block per graph, batch is sorted ----------------
__global__ __launch_bounds__(256) void pool_kernel(const float* __restrict__ out2,
                                                   const int* __restrict__ batch,
                                                   float* __restrict__ out) {
    __shared__ float red[256];
    int g = blockIdx.x;
    int t = threadIdx.x;
    int c = t & 31;
    int sub = t >> 5;
    int beg, end;
    {
        int lo = 0, hi = NNODES;
        while (lo < hi) { int mid = (lo + hi) >> 1; if (batch[mid] < g) lo = mid + 1; else hi = mid; }
        beg = lo;
        lo = beg; hi = NNODES;
        while (lo < hi) { int mid = (lo + hi) >> 1; if (batch[mid] < g + 1) lo = mid + 1; else hi = mid; }
        end = lo;
    }
    float s = 0.f;
    for (int n = beg + sub; n < end; n += 8) s += out2[n * HID + c];
    red[t] = s;
    __syncthreads();
    if (t < 32) {
        float tot = 0.f;
#pragma unroll
        for (int k = 0; k < 8; ++k) tot += red[c + 32 * k];
        int cnt = end - beg;
        out[g * HID + c] = tot / (float)(cnt > 0 ? cnt : 1);
    }
}

extern "C" void kernel_launch(void* const* d_in, const int* in_sizes, int n_in,
                              void* d_out, int out_size, void* d_ws, size_t ws_size,
                              hipStream_t stream) {
    const float* x      = (const float*)d_in[0];
    const int*   ei     = (const int*)d_in[1];
    // d_in[2] = edge_attr (unused)
    const int*   batch  = (const int*)d_in[3];
    const float* W1     = (const float*)d_in[4];
    const float* a_src1 = (const float*)d_in[5];
    const float* a_dst1 = (const float*)d_in[6];
    const float* b1     = (const float*)d_in[7];
    const float* W2     = (const float*)d_in[8];
    const float* a_src2 = (const float*)d_in[9];
    const float* a_dst2 = (const float*)d_in[10];
    const float* b2     = (const float*)d_in[11];
    float* out = (float*)d_out;

    char* ws = (char*)d_ws;
    size_t off = 0;
    auto alloc = [&](size_t bytes) {
        size_t o = off;
        off = (off + bytes + 255) & ~(size_t)255;
        return o;
    };
    unsigned short* h1b = (unsigned short*)(ws + alloc((size_t)NNODES * 256 * 2));
    unsigned short* w1s = (unsigned short*)(ws + alloc((size_t)16 * 4 * 64 * 8 * 2));
    float* out1   = (float*)(ws + alloc((size_t)NNODES * 256 * 4));
    float* h2     = (float*)(ws + alloc((size_t)NNODES * HID * 4));
    float* out2   = (float*)(ws + alloc((size_t)NNODES * HID * 4));
    float* al_s1  = (float*)(ws + alloc((size_t)NNODES * HEADS * 4));
    float* al_d1  = (float*)(ws + alloc((size_t)NNODES * HEADS * 4));
    float* al_s2  = (float*)(ws + alloc((size_t)NNODES * 4));
    float* al_d2  = (float*)(ws + alloc((size_t)NNODES * 4));
    int*   deg    = (int*)(ws + alloc((size_t)NNODES * 4));
    int*   rowst  = (int*)(ws + alloc((size_t)NNODES * 4));
    int*   cursor = (int*)(ws + alloc((size_t)NNODES * 4));
    int*   bsums  = (int*)(ws + alloc(256 * 4));
    int*   boffs  = (int*)(ws + alloc(256 * 4));
    int*   csr    = (int*)(ws + alloc((size_t)NEDGES * 4));
    (void)ws_size;

    int nb_nodes = (NNODES + 255) / 256;      // 196
    int nb_edges = (NEDGES + 255) / 256;      // 3125

    zero_kernel<<<nb_nodes, 256, 0, stream>>>(deg);
    deg_kernel<<<nb_edges, 256, 0, stream>>>(ei, deg);
    scan_block<<<nb_nodes, 256, 0, stream>>>(deg, NNODES, rowst, bsums);
    scan_block<<<1, 256, 0, stream>>>(bsums, nb_nodes, boffs, (int*)nullptr);
    scan_add<<<nb_nodes, 256, 0, stream>>>(rowst, boffs, cursor);
    scatter_kernel<<<nb_edges, 256, 0, stream>>>(ei, cursor, csr);

    w1_swizzle_kernel<<<128, 256, 0, stream>>>(W1, w1s);
    gemm1_mfma_kernel<<<(NNODES + 63) / 64, 256, 0, stream>>>(x, w1s, h1b);
    al1_kernel<<<(NNODES + 3) / 4, 256, 0, stream>>>(h1b, a_src1, a_dst1, al_s1, al_d1);
    gather1_kernel<<<NNODES / 8, 256, 0, stream>>>(h1b, al_s1, al_d1, rowst, csr, b1, out1);

    gemm2_kernel<<<(NNODES + 127) / 128, 256, 0, stream>>>(out1, W2, h2);
    al2_kernel<<<(NNODES + 7) / 8, 256, 0, stream>>>(h2, a_src2, a_dst2, al_s2, al_d2);
    gather2_kernel<<<NNODES / 8, 256, 0, stream>>>(h2, al_s2, al_d2, rowst, csr, b2, out2);
    pool_kernel<<<NG, 256, 0, stream>>>(out2, batch, out);
}

// Round 7
// 362.617 us; speedup vs baseline: 2.6092x; 1.0516x over previous
//
#include <hip/hip_runtime.h>
#include <hip/hip_bf16.h>

#define NNODES 50000
#define NEDGES 800000
#define FIN 128
#define HID 32
#define HEADS 8
#define NG 64
#define NEG_SLOPE 0.2f

using bf16x8 = __attribute__((ext_vector_type(8))) short;   // 8 bf16 (4 VGPRs)
using f32x4  = __attribute__((ext_vector_type(4))) float;   // MFMA acc

static __device__ __forceinline__ float leaky(float x) {
    return x > 0.f ? x : NEG_SLOPE * x;
}
// bf16 helpers (RNE pack, cheap unpack)
static __device__ __forceinline__ unsigned short f2bf(float f) {
    unsigned int x = __float_as_uint(f);
    return (unsigned short)((x + 0x7FFFu + ((x >> 16) & 1u)) >> 16);
}
static __device__ __forceinline__ unsigned int pack2bf(float lo, float hi) {
    return (unsigned int)f2bf(lo) | ((unsigned int)f2bf(hi) << 16);
}
static __device__ __forceinline__ float bfl(unsigned int u) {
    return __uint_as_float(u << 16);
}
static __device__ __forceinline__ float bfh(unsigned int u) {
    return __uint_as_float(u & 0xFFFF0000u);
}

// ---------------- zero init ----------------
__global__ void zero_kernel(int* deg) {
    int i = blockIdx.x * 256 + threadIdx.x;
    if (i < NNODES) deg[i] = 0;
}

// ---------------- degree histogram ----------------
__global__ void deg_kernel(const int* __restrict__ ei, int* __restrict__ deg) {
    int e = blockIdx.x * 256 + threadIdx.x;
    if (e < NEDGES) {
        int d = ei[NEDGES + e];
        atomicAdd(&deg[d], 1);
    }
}

// ---------------- block-wise exclusive scan ----------------
__global__ void scan_block(const int* __restrict__ in, int n, int* __restrict__ out_excl,
                           int* __restrict__ bsums) {
    __shared__ int s[256];
    int t = threadIdx.x;
    int i = blockIdx.x * 256 + t;
    int v = (i < n) ? in[i] : 0;
    s[t] = v;
    __syncthreads();
    for (int off = 1; off < 256; off <<= 1) {
        int x = (t >= off) ? s[t - off] : 0;
        __syncthreads();
        s[t] += x;
        __syncthreads();
    }
    if (i < n) out_excl[i] = s[t] - v;
    if (bsums && t == 255) bsums[blockIdx.x] = s[255];
}

__global__ void scan_add(int* __restrict__ row, const int* __restrict__ boffs,
                         int* __restrict__ cursor) {
    int i = blockIdx.x * 256 + threadIdx.x;
    if (i < NNODES) {
        int r = row[i] + boffs[blockIdx.x];
        row[i] = r;
        cursor[i] = r;
    }
}

// ---------------- scatter edges into CSR ----------------
__global__ void scatter_kernel(const int* __restrict__ ei, int* __restrict__ cursor,
                               int* __restrict__ csr_src) {
    int e = blockIdx.x * 256 + threadIdx.x;
    if (e < NEDGES) {
        int s = ei[e];
        int d = ei[NEDGES + e];
        int pos = atomicAdd(&cursor[d], 1);
        csr_src[pos] = s;
    }
}

// ---------------- W1 pre-swizzle into B-fragment order (bf16) ----------------
// w1s[((ct*4 + ks)*64 + lane)*8 + j] = bf16( W1[ ks*32 + (lane>>4)*8 + j ][ ct*16 + (lane&15) ] )
__global__ void w1_swizzle_kernel(const float* __restrict__ W, unsigned short* __restrict__ w1s) {
    int idx = blockIdx.x * 256 + threadIdx.x;   // 0..32767
    if (idx >= 16 * 4 * 64 * 8) return;
    int j    = idx & 7;
    int lane = (idx >> 3) & 63;
    int ks   = (idx >> 9) & 3;
    int ct   = idx >> 11;
    int k = ks * 32 + (lane >> 4) * 8 + j;
    int n = ct * 16 + (lane & 15);
    w1s[idx] = f2bf(W[k * 256 + n]);
}

// ---------------- W2 pre-swizzle (K=256 -> 8 k-steps, N=32 -> 2 col-tiles) ----------------
__global__ void w2_swizzle_kernel(const float* __restrict__ W, unsigned short* __restrict__ w2s) {
    int idx = blockIdx.x * 256 + threadIdx.x;   // 0..8191
    if (idx >= 2 * 8 * 64 * 8) return;
    int j    = idx & 7;
    int lane = (idx >> 3) & 63;
    int ks   = (idx >> 9) & 7;
    int ct   = idx >> 12;
    int k = ks * 32 + (lane >> 4) * 8 + j;
    int n = ct * 16 + (lane & 15);
    w2s[idx] = f2bf(W[k * 32 + n]);
}

// ---------------- GEMM1 via MFMA + fused al1 ----------------
// 4 waves/block; wave w owns cols w*64..+63 (heads 2w,2w+1). Block covers 64 rows.
__global__ __launch_bounds__(256) void gemm1_mfma_kernel(const float* __restrict__ x,
                                                         const unsigned short* __restrict__ w1s,
                                                         const float* __restrict__ a_src,
                                                         const float* __restrict__ a_dst,
                                                         unsigned short* __restrict__ h1b,
                                                         float* __restrict__ al_s,
                                                         float* __restrict__ al_d) {
    __shared__ unsigned short lds[4][16 * 64];   // 2 KB per wave
    int t = threadIdx.x;
    int w = t >> 6;
    int l = t & 63;
    int lane16 = l & 15, quad = l >> 4;

    // B-fragments: 4 col-tiles x 4 k-steps (register-resident, L2-hot)
    bf16x8 bf[4][4];
    const bf16x8* wp = (const bf16x8*)w1s;
#pragma unroll
    for (int ct = 0; ct < 4; ++ct)
#pragma unroll
        for (int ks = 0; ks < 4; ++ks)
            bf[ct][ks] = wp[((w * 4 + ct) * 4 + ks) * 64 + l];

    // attention vectors for this wave's 4 col-tiles
    float as_c[4], ad_c[4];
#pragma unroll
    for (int ct = 0; ct < 4; ++ct) {
        int col = w * 64 + ct * 16 + lane16;
        as_c[ct] = a_src[col];
        ad_c[ct] = a_dst[col];
    }

    int rbase = blockIdx.x * 64;
    for (int rg = 0; rg < 4; ++rg) {
        int row0 = rbase + rg * 16;
        int r = row0 + lane16;
        int r_eff = r < NNODES ? r : NNODES - 1;   // clamp reads; stores guarded
        bf16x8 af[4];
#pragma unroll
        for (int ks = 0; ks < 4; ++ks) {
            const float* ap = x + (size_t)r_eff * FIN + ks * 32 + quad * 8;
            float4 a0 = *(const float4*)ap;
            float4 a1 = *(const float4*)(ap + 4);
            bf16x8 v;
            v[0] = (short)f2bf(a0.x); v[1] = (short)f2bf(a0.y);
            v[2] = (short)f2bf(a0.z); v[3] = (short)f2bf(a0.w);
            v[4] = (short)f2bf(a1.x); v[5] = (short)f2bf(a1.y);
            v[6] = (short)f2bf(a1.z); v[7] = (short)f2bf(a1.w);
            af[ks] = v;
        }
        f32x4 acc[4];
#pragma unroll
        for (int ct = 0; ct < 4; ++ct) acc[ct] = (f32x4){0.f, 0.f, 0.f, 0.f};
#pragma unroll
        for (int ks = 0; ks < 4; ++ks)
#pragma unroll
            for (int ct = 0; ct < 4; ++ct)
                acc[ct] = __builtin_amdgcn_mfma_f32_16x16x32_bf16(af[ks], bf[ct][ks], acc[ct], 0, 0, 0);

        // fused al1: rows quad*4+reg; head 2w (ct 0,1), head 2w+1 (ct 2,3)
#pragma unroll
        for (int reg = 0; reg < 4; ++reg) {
            float ps0 = acc[0][reg] * as_c[0] + acc[1][reg] * as_c[1];
            float ps1 = acc[2][reg] * as_c[2] + acc[3][reg] * as_c[3];
            float pd0 = acc[0][reg] * ad_c[0] + acc[1][reg] * ad_c[1];
            float pd1 = acc[2][reg] * ad_c[2] + acc[3][reg] * ad_c[3];
#pragma unroll
            for (int m = 1; m < 16; m <<= 1) {
                ps0 += __shfl_xor(ps0, m); ps1 += __shfl_xor(ps1, m);
                pd0 += __shfl_xor(pd0, m); pd1 += __shfl_xor(pd1, m);
            }
            int gr = row0 + quad * 4 + reg;
            if (lane16 == 0 && gr < NNODES) {
                al_s[gr * HEADS + 2 * w]     = ps0;
                al_s[gr * HEADS + 2 * w + 1] = ps1;
                al_d[gr * HEADS + 2 * w]     = pd0;
                al_d[gr * HEADS + 2 * w + 1] = pd1;
            }
        }

        // epilogue: C/D col=lane16, row=quad*4+reg -> LDS transpose (wave-private)
        unsigned short* lw = lds[w];
#pragma unroll
        for (int ct = 0; ct < 4; ++ct)
#pragma unroll
            for (int reg = 0; reg < 4; ++reg)
                lw[(quad * 4 + reg) * 64 + ct * 16 + lane16] = f2bf(acc[ct][reg]);
        int row_l = l >> 2;
        int ch = l & 3;
        int gr = row0 + row_l;
        if (gr < NNODES) {
            const uint4* srcp = (const uint4*)(lw + row_l * 64 + ch * 16);
            uint4 d0 = srcp[0];
            uint4 d1 = srcp[1];
            uint4* dst = (uint4*)(h1b + (size_t)gr * 256 + w * 64 + ch * 16);
            dst[0] = d0;
            dst[1] = d1;
        }
    }
}

// ---------------- gather layer 1: 32 lanes/node (2 nodes/wave), bf16 in, bf16 out ----------------
__global__ __launch_bounds__(256) void gather1_kernel(const unsigned short* __restrict__ h1b,
                                                      const float* __restrict__ al_s,
                                                      const float* __restrict__ al_d,
                                                      const int* __restrict__ row_start,
                                                      const int* __restrict__ csr_src,
                                                      const float* __restrict__ b1,
                                                      unsigned short* __restrict__ out1b) {
    int t = threadIdx.x;
    int l = t & 63;
    int q = l & 31;
    int base = l & 32;
    int n = blockIdx.x * 8 + (t >> 5);
    int e_st = q >> 3;
    int h_st = q & 7;
    int h_f  = q >> 2;
    float ad_st = al_d[n * HEADS + h_st];

    float p = __expf(leaky(al_s[n * HEADS + h_f] + al_d[n * HEADS + h_f]));
    float z = p;
    float acc[8];
    {
        uint4 v = *(const uint4*)(h1b + (size_t)n * 256 + q * 8);
        acc[0] = p * bfl(v.x); acc[1] = p * bfh(v.x);
        acc[2] = p * bfl(v.y); acc[3] = p * bfh(v.y);
        acc[4] = p * bfl(v.z); acc[5] = p * bfh(v.z);
        acc[6] = p * bfl(v.w); acc[7] = p * bfh(v.w);
    }

    int beg = row_start[n];
    int end = (n + 1 < NNODES) ? row_start[n + 1] : NEDGES;
    for (int i = beg; i < end; i += 4) {
        int rem = end - i;
        int src4 = n;
        float pe4 = 0.f;
        if (e_st < rem) {
            src4 = csr_src[i + e_st];
            pe4 = __expf(leaky(al_s[src4 * HEADS + h_st] + ad_st));
        }
#pragma unroll
        for (int j = 0; j < 4; ++j) {
            int   sj  = __shfl(src4, base + j * 8);
            float pej = __shfl(pe4, base + j * 8 + h_f);
            uint4 v = *(const uint4*)(h1b + (size_t)sj * 256 + q * 8);
            z += pej;
            acc[0] += pej * bfl(v.x); acc[1] += pej * bfh(v.x);
            acc[2] += pej * bfl(v.y); acc[3] += pej * bfh(v.y);
            acc[4] += pej * bfl(v.z); acc[5] += pej * bfh(v.z);
            acc[6] += pej * bfl(v.w); acc[7] += pej * bfh(v.w);
        }
    }
    float inv = 1.0f / z;
    float4 b0 = *(const float4*)(b1 + q * 8);
    float4 b2 = *(const float4*)(b1 + q * 8 + 4);
    float o[8];
    o[0] = acc[0] * inv + b0.x; o[1] = acc[1] * inv + b0.y;
    o[2] = acc[2] * inv + b0.z; o[3] = acc[3] * inv + b0.w;
    o[4] = acc[4] * inv + b2.x; o[5] = acc[5] * inv + b2.y;
    o[6] = acc[6] * inv + b2.z; o[7] = acc[7] * inv + b2.w;
#pragma unroll
    for (int k = 0; k < 8; ++k) o[k] = o[k] > 0.f ? o[k] : 0.f;
    uint4 pk;
    pk.x = pack2bf(o[0], o[1]); pk.y = pack2bf(o[2], o[3]);
    pk.z = pack2bf(o[4], o[5]); pk.w = pack2bf(o[6], o[7]);
    *(uint4*)(out1b + (size_t)n * 256 + q * 8) = pk;
}

// ---------------- GEMM2 via MFMA + fused al2 ----------------
// 4 waves/block, each wave owns 16 rows; 2 col-tiles x 8 k-steps B-frags in registers.
__global__ __launch_bounds__(256) void gemm2_mfma_kernel(const unsigned short* __restrict__ out1b,
                                                         const unsigned short* __restrict__ w2s,
                                                         const float* __restrict__ a_src,
                                                         const float* __restrict__ a_dst,
                                                         float* __restrict__ h2,
                                                         float* __restrict__ al_s,
                                                         float* __restrict__ al_d) {
    int t = threadIdx.x;
    int w = t >> 6;
    int l = t & 63;
    int lane16 = l & 15, quad = l >> 4;

    bf16x8 bf[2][8];
    const bf16x8* wp = (const bf16x8*)w2s;
#pragma unroll
    for (int ct = 0; ct < 2; ++ct)
#pragma unroll
        for (int ks = 0; ks < 8; ++ks)
            bf[ct][ks] = wp[((ct * 8 + ks)) * 64 + l];

    float as_c[2], ad_c[2];
#pragma unroll
    for (int ct = 0; ct < 2; ++ct) {
        as_c[ct] = a_src[ct * 16 + lane16];
        ad_c[ct] = a_dst[ct * 16 + lane16];
    }

    int row0 = blockIdx.x * 64 + w * 16;
    int r = row0 + lane16;
    int r_eff = r < NNODES ? r : NNODES - 1;
    f32x4 acc[2];
    acc[0] = (f32x4){0.f, 0.f, 0.f, 0.f};
    acc[1] = (f32x4){0.f, 0.f, 0.f, 0.f};
#pragma unroll
    for (int ks = 0; ks < 8; ++ks) {
        bf16x8 af = *(const bf16x8*)(out1b + (size_t)r_eff * 256 + ks * 32 + quad * 8);
        acc[0] = __builtin_amdgcn_mfma_f32_16x16x32_bf16(af, bf[0][ks], acc[0], 0, 0, 0);
        acc[1] = __builtin_amdgcn_mfma_f32_16x16x32_bf16(af, bf[1][ks], acc[1], 0, 0, 0);
    }
#pragma unroll
    for (int reg = 0; reg < 4; ++reg) {
        int gr = row0 + quad * 4 + reg;
        if (gr < NNODES) {
            h2[(size_t)gr * 32 + lane16]      = acc[0][reg];
            h2[(size_t)gr * 32 + 16 + lane16] = acc[1][reg];
        }
        float ps = acc[0][reg] * as_c[0] + acc[1][reg] * as_c[1];
        float pd = acc[0][reg] * ad_c[0] + acc[1][reg] * ad_c[1];
#pragma unroll
        for (int m = 1; m < 16; m <<= 1) {
            ps += __shfl_xor(ps, m);
            pd += __shfl_xor(pd, m);
        }
        if (lane16 == 0 && gr < NNODES) {
            al_s[gr] = ps;
            al_d[gr] = pd;
        }
    }
}

// ---------------- gather layer 2: staged exp + shfl broadcast, no atomics ----------------
__global__ __launch_bounds__(256) void gather2_kernel(const float* __restrict__ h2,
                                                      const float* __restrict__ al_s,
                                                      const float* __restrict__ al_d,
                                                      const int* __restrict__ row_start,
                                                      const int* __restrict__ csr_src,
                                                      const float* __restrict__ b2,
                                                      float* __restrict__ out2) {
    int t = threadIdx.x;
    int l = t & 63;
    int c = l & 31;
    int base = l & 32;
    int n = blockIdx.x * 8 + (t >> 5);
    float ad = al_d[n];
    float p = __expf(leaky(al_s[n] + ad));
    float z = p;
    float acc = p * h2[n * HID + c];
    int beg = row_start[n];
    int end = (n + 1 < NNODES) ? row_start[n + 1] : NEDGES;
    for (int i = beg; i < end; i += 32) {
        int rem = end - i;
        int src = n;
        float pe = 0.f;
        if (c < rem) {
            src = csr_src[i + c];
            pe = __expf(leaky(al_s[src] + ad));
        }
        int m = rem < 32 ? rem : 32;
        for (int j = 0; j < m; ++j) {
            int   sj  = __shfl(src, base + j);
            float pej = __shfl(pe, base + j);
            z += pej;
            acc += pej * h2[sj * HID + c];
        }
    }
    out2[n * HID + c] = acc / z + b2[c];
}

// ---------------- mean-pool: one block per graph, batch is sorted ----------------
__global__ __launch_bounds__(256) void pool_kernel(const float* __restrict__ out2,
                                                   const int* __restrict__ batch,
                                                   float* __restrict__ out) {
    __shared__ float red[256];
    int g = blockIdx.x;
    int t = threadIdx.x;
    int c = t & 31;
    int sub = t >> 5;
    int beg, end;
    {
        int lo = 0, hi = NNODES;
        while (lo < hi) { int mid = (lo + hi) >> 1; if (batch[mid] < g) lo = mid + 1; else hi = mid; }
        beg = lo;
        lo = beg; hi = NNODES;
        while (lo < hi) { int mid = (lo + hi) >> 1; if (batch[mid] < g + 1) lo = mid + 1; else hi = mid; }
        end = lo;
    }
    float s = 0.f;
    for (int n = beg + sub; n < end; n += 8) s += out2[n * HID + c];
    red[t] = s;
    __syncthreads();
    if (t < 32) {
        float tot = 0.f;
#pragma unroll
        for (int k = 0; k < 8; ++k) tot += red[c + 32 * k];
        int cnt = end - beg;
        out[g * HID + c] = tot / (float)(cnt > 0 ? cnt : 1);
    }
}

extern "C" void kernel_launch(void* const* d_in, const int* in_sizes, int n_in,
                              void* d_out, int out_size, void* d_ws, size_t ws_size,
                              hipStream_t stream) {
    const float* x      = (const float*)d_in[0];
    const int*   ei     = (const int*)d_in[1];
    // d_in[2] = edge_attr (unused)
    const int*   batch  = (const int*)d_in[3];
    const float* W1     = (const float*)d_in[4];
    const float* a_src1 = (const float*)d_in[5];
    const float* a_dst1 = (const float*)d_in[6];
    const float* b1     = (const float*)d_in[7];
    const float* W2     = (const float*)d_in[8];
    const float* a_src2 = (const float*)d_in[9];
    const float* a_dst2 = (const float*)d_in[10];
    const float* b2     = (const float*)d_in[11];
    float* out = (float*)d_out;

    char* ws = (char*)d_ws;
    size_t off = 0;
    auto alloc = [&](size_t bytes) {
        size_t o = off;
        off = (off + bytes + 255) & ~(size_t)255;
        return o;
    };
    unsigned short* h1b   = (unsigned short*)(ws + alloc((size_t)NNODES * 256 * 2));
    unsigned short* out1b = (unsigned short*)(ws + alloc((size_t)NNODES * 256 * 2));
    unsigned short* w1s   = (unsigned short*)(ws + alloc((size_t)16 * 4 * 64 * 8 * 2));
    unsigned short* w2s   = (unsigned short*)(ws + alloc((size_t)2 * 8 * 64 * 8 * 2));
    float* h2     = (float*)(ws + alloc((size_t)NNODES * HID * 4));
    float* out2   = (float*)(ws + alloc((size_t)NNODES * HID * 4));
    float* al_s1  = (float*)(ws + alloc((size_t)NNODES * HEADS * 4));
    float* al_d1  = (float*)(ws + alloc((size_t)NNODES * HEADS * 4));
    float* al_s2  = (float*)(ws + alloc((size_t)NNODES * 4));
    float* al_d2  = (float*)(ws + alloc((size_t)NNODES * 4));
    int*   deg    = (int*)(ws + alloc((size_t)NNODES * 4));
    int*   rowst  = (int*)(ws + alloc((size_t)NNODES * 4));
    int*   cursor = (int*)(ws + alloc((size_t)NNODES * 4));
    int*   bsums  = (int*)(ws + alloc(256 * 4));
    int*   boffs  = (int*)(ws + alloc(256 * 4));
    int*   csr    = (int*)(ws + alloc((size_t)NEDGES * 4));
    (void)ws_size;

    int nb_nodes = (NNODES + 255) / 256;      // 196
    int nb_edges = (NEDGES + 255) / 256;      // 3125

    zero_kernel<<<nb_nodes, 256, 0, stream>>>(deg);
    deg_kernel<<<nb_edges, 256, 0, stream>>>(ei, deg);
    scan_block<<<nb_nodes, 256, 0, stream>>>(deg, NNODES, rowst, bsums);
    scan_block<<<1, 256, 0, stream>>>(bsums, nb_nodes, boffs, (int*)nullptr);
    scan_add<<<nb_nodes, 256, 0, stream>>>(rowst, boffs, cursor);
    scatter_kernel<<<nb_edges, 256, 0, stream>>>(ei, cursor, csr);

    w1_swizzle_kernel<<<128, 256, 0, stream>>>(W1, w1s);
    w2_swizzle_kernel<<<32, 256, 0, stream>>>(W2, w2s);
    gemm1_mfma_kernel<<<(NNODES + 63) / 64, 256, 0, stream>>>(x, w1s, a_src1, a_dst1,
                                                              h1b, al_s1, al_d1);
    gather1_kernel<<<NNODES / 8, 256, 0, stream>>>(h1b, al_s1, al_d1, rowst, csr, b1, out1b);

    gemm2_mfma_kernel<<<(NNODES + 63) / 64, 256, 0, stream>>>(out1b, w2s, a_src2, a_dst2,
                                                              h2, al_s2, al_d2);
    gather2_kernel<<<NNODES / 8, 256, 0, stream>>>(h2, al_s2, al_d2, rowst, csr, b2, out2);
    pool_kernel<<<NG, 256, 0, stream>>>(out2, batch, out);
}